// Round 1
// baseline (1159.601 us; speedup 1.0000x reference)
//
#include <hip/hip_runtime.h>
#include <hip/hip_bf16.h>
#include <math.h>

#define NN 50000
#define NE 400000
#define DIM 64
#define HEADS 4
#define SIC 0.5f

// ---------------- K0: transpose W,Q into [m][i][o] interleaved complex ----------------
__global__ void k0_transpose(const float* __restrict__ Wre, const float* __restrict__ Wim,
                             const float* __restrict__ Qre, const float* __restrict__ Qim,
                             float2* __restrict__ WTw, float2* __restrict__ WTq) {
    int tid = blockIdx.x * blockDim.x + threadIdx.x;
    if (tid >= HEADS * DIM * DIM) return;
    int m = tid >> 12;            // tid = m*4096 + o*64 + i
    int rem = tid & 4095;
    int o = rem >> 6, i = rem & 63;
    int didx = (m * DIM + i) * DIM + o;
    WTw[didx] = make_float2(Wre[tid], Wim[tid]);
    WTq[didx] = make_float2(Qre[tid], Qim[tid]);
}

// ---------------- K1: per-node Wh = Wm h, Qh = Qm h, t = Qh^H h, norm2 ----------------
__global__ __launch_bounds__(256) void k1_precompute(
    const float* __restrict__ h_re, const float* __restrict__ h_im,
    const float2* __restrict__ WTw, const float2* __restrict__ WTq,
    float2* __restrict__ Wh, float2* __restrict__ Qh,
    float2* __restrict__ t_out, float* __restrict__ norm2_out) {
    __shared__ float2 h_lds[8][DIM];
    int nbase = blockIdx.x * 8;
    int t = threadIdx.x;
    for (int k = t; k < 8 * DIM; k += 256) {
        int nb = k >> 6, d = k & 63;
        int n = nbase + nb;
        float2 v = make_float2(0.f, 0.f);
        if (n < NN) v = make_float2(h_re[n * DIM + d], h_im[n * DIM + d]);
        h_lds[nb][d] = v;
    }
    __syncthreads();
    int wave = t >> 6;   // head
    int lane = t & 63;   // output dim
    float2 accW[8], accQ[8];
#pragma unroll
    for (int nb = 0; nb < 8; ++nb) { accW[nb] = make_float2(0, 0); accQ[nb] = make_float2(0, 0); }
    const float2* wtw = WTw + wave * DIM * DIM;
    const float2* wtq = WTq + wave * DIM * DIM;
    for (int i = 0; i < DIM; ++i) {
        float2 w1 = wtw[i * DIM + lane];
        float2 q1 = wtq[i * DIM + lane];
#pragma unroll
        for (int nb = 0; nb < 8; ++nb) {
            float2 hv = h_lds[nb][i];
            accW[nb].x += hv.x * w1.x - hv.y * w1.y;
            accW[nb].y += hv.x * w1.y + hv.y * w1.x;
            accQ[nb].x += hv.x * q1.x - hv.y * q1.y;
            accQ[nb].y += hv.x * q1.y + hv.y * q1.x;
        }
    }
    // t[n][m] = sum_o conj(Qh)*h
    float tv[16];
#pragma unroll
    for (int nb = 0; nb < 8; ++nb) {
        float2 hv = h_lds[nb][lane];
        tv[2 * nb]     = accQ[nb].x * hv.x + accQ[nb].y * hv.y;
        tv[2 * nb + 1] = accQ[nb].x * hv.y - accQ[nb].y * hv.x;
    }
    for (int off = 32; off; off >>= 1) {
#pragma unroll
        for (int k = 0; k < 16; ++k) tv[k] += __shfl_xor(tv[k], off, 64);
    }
#pragma unroll
    for (int nb = 0; nb < 8; ++nb) {
        int n = nbase + nb;
        if (n < NN) {
            Wh[(n * HEADS + wave) * DIM + lane] = accW[nb];
            Qh[(n * HEADS + wave) * DIM + lane] = accQ[nb];
            if (lane == 0) t_out[n * HEADS + wave] = make_float2(tv[2 * nb], tv[2 * nb + 1]);
        }
    }
    if (wave == 0) {
        float nv[8];
#pragma unroll
        for (int nb = 0; nb < 8; ++nb) { float2 hv = h_lds[nb][lane]; nv[nb] = hv.x * hv.x + hv.y * hv.y; }
        for (int off = 32; off; off >>= 1) {
#pragma unroll
            for (int k = 0; k < 8; ++k) nv[k] += __shfl_xor(nv[k], off, 64);
        }
        if (lane == 0) {
#pragma unroll
            for (int nb = 0; nb < 8; ++nb) { int n = nbase + nb; if (n < NN) norm2_out[n] = fmaxf(nv[nb], 1e-6f); }
        }
    }
}

// ---------------- CSR build ----------------
__global__ void k2a_count(const int* __restrict__ dst, int* __restrict__ counts) {
    int e = blockIdx.x * blockDim.x + threadIdx.x;
    if (e < NE) atomicAdd(&counts[dst[e]], 1);
}

__global__ __launch_bounds__(1024) void k2b_scan(const int* __restrict__ counts,
                                                 int* __restrict__ row_ptr, int* __restrict__ cursor) {
    __shared__ int buf[1024];
    __shared__ int s_run;
    int t = threadIdx.x;
    if (t == 0) s_run = 0;
    __syncthreads();
    for (int base = 0; base < NN; base += 1024) {
        int run = s_run;
        int idx = base + t;
        int v = (idx < NN) ? counts[idx] : 0;
        buf[t] = v;
        __syncthreads();
        for (int off = 1; off < 1024; off <<= 1) {
            int x = 0;
            if (t >= off) x = buf[t - off];
            __syncthreads();
            if (t >= off) buf[t] += x;
            __syncthreads();
        }
        int excl = buf[t] - v;
        if (idx < NN) { row_ptr[idx] = run + excl; cursor[idx] = run + excl; }
        int total = buf[1023];
        __syncthreads();
        if (t == 0) s_run = run + total;
        __syncthreads();
    }
    if (t == 0) row_ptr[NN] = s_run;
}

__global__ void k2c_fill(const int* __restrict__ src, const int* __restrict__ dst,
                         int* __restrict__ cursor, int* __restrict__ sorted_src) {
    int e = blockIdx.x * blockDim.x + threadIdx.x;
    if (e < NE) {
        int pos = atomicAdd(&cursor[dst[e]], 1);
        sorted_src[pos] = src[e];
    }
}

// ---------------- K_main: per-node fused edge pass (wave per node, 4 heads/wave) ----------------
__global__ __launch_bounds__(256) void k_main(
    const float* __restrict__ h_re, const float* __restrict__ h_im,
    const float2* __restrict__ Wh, float2* Qh_S /* read Qh, write S in place */,
    const float2* __restrict__ t_in, const float* __restrict__ norm2_in,
    const int* __restrict__ row_ptr, const int* __restrict__ sorted_src,
    float2* __restrict__ T_out) {
    int wave = threadIdx.x >> 6;
    int lane = threadIdx.x & 63;
    int n = blockIdx.x * 4 + wave;
    if (n >= NN) return;
    float2 hd = make_float2(h_re[n * DIM + lane], h_im[n * DIM + lane]);
    float2 qh[HEADS], tnm[HEADS];
#pragma unroll
    for (int m = 0; m < HEADS; ++m) {
        qh[m] = Qh_S[(n * HEADS + m) * DIM + lane];
        tnm[m] = t_in[n * HEADS + m];
    }
    float inv_n2 = 1.0f / norm2_in[n];
    int beg = row_ptr[n], end = row_ptr[n + 1];
    float m_run[HEADS], l_run[HEADS];
    float2 S[HEADS], T[HEADS];
#pragma unroll
    for (int m = 0; m < HEADS; ++m) {
        m_run[m] = -INFINITY; l_run[m] = 0.f;
        S[m] = make_float2(0, 0); T[m] = make_float2(0, 0);
    }
    for (int pos = beg; pos < end; ++pos) {
        int s = sorted_src[pos];
        float2 hs = make_float2(h_re[s * DIM + lane], h_im[s * DIM + lane]);
        float2 whs[HEADS];
#pragma unroll
        for (int m = 0; m < HEADS; ++m) whs[m] = Wh[(s * HEADS + m) * DIM + lane];
        float red[17];
        red[16] = hd.x * hs.x;
#pragma unroll
        for (int m = 0; m < HEADS; ++m) {
            red[4 * m + 0] = hd.x * whs[m].x + hd.y * whs[m].y;   // dot = conj(hd).Wh  (re)
            red[4 * m + 1] = hd.x * whs[m].y - hd.y * whs[m].x;   // (im)
            red[4 * m + 2] = qh[m].x * whs[m].x + qh[m].y * whs[m].y; // term1 = conj(Qh).Wh (re)
            red[4 * m + 3] = qh[m].x * whs[m].y - qh[m].y * whs[m].x; // (im)
        }
        for (int off = 32; off; off >>= 1) {
#pragma unroll
            for (int k = 0; k < 17; ++k) red[k] += __shfl_xor(red[k], off, 64);
        }
        float simdot = red[16];
        float sg = (simdot > 0.f) ? 1.f : ((simdot < 0.f) ? 0.f : 0.5f);
#pragma unroll
        for (int m = 0; m < HEADS; ++m) {
            float cre = SIC * red[4 * m + 0] * inv_n2;
            float cim = SIC * red[4 * m + 1] * inv_n2;
            float sre = red[4 * m + 2] - (cre * tnm[m].x - cim * tnm[m].y);
            float sim_ = red[4 * m + 3] - (cre * tnm[m].y + cim * tnm[m].x);
            float logit = sqrtf(sre * sre + sim_ * sim_) * 0.125f;  // GAMMA/sqrt(D)
            if (logit > m_run[m]) {
                float f = expf(m_run[m] - logit);  // exp(-inf)=0 on first edge
                S[m].x *= f; S[m].y *= f; T[m].x *= f; T[m].y *= f; l_run[m] *= f;
                m_run[m] = logit;
            }
            float ex = expf(logit - m_run[m]);
            l_run[m] += ex;
            float w = ex * sg;
            S[m].x += w * hs.x; S[m].y += w * hs.y;
            T[m].x += w * cre;  T[m].y += w * cim;
        }
    }
#pragma unroll
    for (int m = 0; m < HEADS; ++m) {
        float inv = 1.0f / (l_run[m] + 1e-16f);
        Qh_S[(n * HEADS + m) * DIM + lane] = make_float2(S[m].x * inv, S[m].y * inv);
        if (lane == 0) T_out[n * HEADS + m] = make_float2(T[m].x * inv, T[m].y * inv);
    }
}

// ---------------- K5: updates = sum_m Wm@S - gate*Tsum*h; NodeNorm; ModReLU ----------------
__global__ __launch_bounds__(256) void k5_finish(
    const float* __restrict__ h_re, const float* __restrict__ h_im,
    const float2* __restrict__ S_in, const float2* __restrict__ T_in,
    const float2* __restrict__ WTw,
    const float* __restrict__ gate_raw, const float* __restrict__ modrelu_b,
    float2* __restrict__ out) {
    __shared__ float2 S_lds[32][HEADS][DIM];  // 64 KiB
    int t = threadIdx.x;
    int nbase = blockIdx.x * 32;
    for (int k = t; k < 32 * HEADS * DIM; k += 256) {
        long gidx = (long)nbase * HEADS * DIM + k;
        float2 v = make_float2(0, 0);
        if (gidx < (long)NN * HEADS * DIM) v = S_in[gidx];
        ((float2*)S_lds)[k] = v;
    }
    __syncthreads();
    int wave = t >> 6, lane = t & 63;
    float gate = 1.0f / (1.0f + expf(-gate_raw[0]));
    float b = modrelu_b[lane];
    float2 U[8];
#pragma unroll
    for (int nb = 0; nb < 8; ++nb) U[nb] = make_float2(0, 0);
    for (int m = 0; m < HEADS; ++m) {
        const float2* wt = WTw + m * DIM * DIM;
        for (int i = 0; i < DIM; ++i) {
            float2 w1 = wt[i * DIM + lane];
#pragma unroll
            for (int nb = 0; nb < 8; ++nb) {
                float2 s = S_lds[wave * 8 + nb][m][i];
                U[nb].x += s.x * w1.x - s.y * w1.y;
                U[nb].y += s.x * w1.y + s.y * w1.x;
            }
        }
    }
#pragma unroll
    for (int nb = 0; nb < 8; ++nb) {
        int nl = wave * 8 + nb;
        int n = nbase + nl;
        float2 Ts = make_float2(0, 0);
        float2 hv = make_float2(0, 0);
        if (n < NN) {
#pragma unroll
            for (int m = 0; m < HEADS; ++m) { float2 tv = T_in[n * HEADS + m]; Ts.x += tv.x; Ts.y += tv.y; }
            hv = make_float2(h_re[n * DIM + lane], h_im[n * DIM + lane]);
        }
        float hre = hv.x + U[nb].x - gate * (Ts.x * hv.x - Ts.y * hv.y);
        float him = hv.y + U[nb].y - gate * (Ts.x * hv.y + Ts.y * hv.x);
        // NodeNorm over D (ddof=1)
        float r4[4] = {hre, him, hre * hre, him * him};
        for (int off = 32; off; off >>= 1) {
#pragma unroll
            for (int k = 0; k < 4; ++k) r4[k] += __shfl_xor(r4[k], off, 64);
        }
        float mean_r = r4[0] * (1.f / DIM), mean_i = r4[1] * (1.f / DIM);
        float var_r = (r4[2] - DIM * mean_r * mean_r) * (1.f / (DIM - 1));
        float var_i = (r4[3] - DIM * mean_i * mean_i) * (1.f / (DIM - 1));
        float std_r = fmaxf(sqrtf(fmaxf(var_r, 0.f)), 1e-5f);
        float std_i = fmaxf(sqrtf(fmaxf(var_i, 0.f)), 1e-5f);
        float xr = (hre - mean_r) / std_r;
        float xi = (him - mean_i) / std_i;
        // ModReLU
        float mag = fmaxf(sqrtf(xr * xr + xi * xi), 1e-6f);
        float g = fmaxf(mag + b, 0.f);
        float sc = g / mag;
        if (n < NN) out[n * DIM + lane] = make_float2(xr * sc, xi * sc);
    }
}

extern "C" void kernel_launch(void* const* d_in, const int* in_sizes, int n_in,
                              void* d_out, int out_size, void* d_ws, size_t ws_size,
                              hipStream_t stream) {
    const float* h_re = (const float*)d_in[0];
    const float* h_im = (const float*)d_in[1];
    const float* W_re = (const float*)d_in[2];
    const float* W_im = (const float*)d_in[3];
    const float* Q_re = (const float*)d_in[4];
    const float* Q_im = (const float*)d_in[5];
    const float* gate_raw = (const float*)d_in[6];
    const float* b = (const float*)d_in[7];
    const int* src = (const int*)d_in[8];
    const int* dst = (const int*)d_in[9];

    char* ws = (char*)d_ws;
    size_t off = 0;
    auto alloc = [&](size_t bytes) {
        void* p = ws + off;
        off = (off + bytes + 255) & ~(size_t)255;
        return p;
    };
    float2* WTw = (float2*)alloc((size_t)HEADS * DIM * DIM * sizeof(float2));
    float2* WTq = (float2*)alloc((size_t)HEADS * DIM * DIM * sizeof(float2));
    float2* Wh = (float2*)alloc((size_t)NN * HEADS * DIM * sizeof(float2));
    float2* Qh = (float2*)alloc((size_t)NN * HEADS * DIM * sizeof(float2));  // reused as S
    float2* t_buf = (float2*)alloc((size_t)NN * HEADS * sizeof(float2));
    float* norm2 = (float*)alloc((size_t)NN * sizeof(float));
    float2* T_buf = (float2*)alloc((size_t)NN * HEADS * sizeof(float2));
    int* counts = (int*)alloc((size_t)NN * sizeof(int));
    int* row_ptr = (int*)alloc((size_t)(NN + 1) * sizeof(int));
    int* cursor = (int*)alloc((size_t)NN * sizeof(int));
    int* sorted_src = (int*)alloc((size_t)NE * sizeof(int));

    hipMemsetAsync(counts, 0, (size_t)NN * sizeof(int), stream);
    k0_transpose<<<(HEADS * DIM * DIM + 255) / 256, 256, 0, stream>>>(W_re, W_im, Q_re, Q_im, WTw, WTq);
    k1_precompute<<<(NN + 7) / 8, 256, 0, stream>>>(h_re, h_im, WTw, WTq, Wh, Qh, t_buf, norm2);
    k2a_count<<<(NE + 255) / 256, 256, 0, stream>>>(dst, counts);
    k2b_scan<<<1, 1024, 0, stream>>>(counts, row_ptr, cursor);
    k2c_fill<<<(NE + 255) / 256, 256, 0, stream>>>(src, dst, cursor, sorted_src);
    k_main<<<(NN + 3) / 4, 256, 0, stream>>>(h_re, h_im, Wh, Qh, t_buf, norm2, row_ptr, sorted_src, T_buf);
    k5_finish<<<(NN + 31) / 32, 256, 0, stream>>>(h_re, h_im, Qh, T_buf, WTw, gate_raw, b, (float2*)d_out);
}

// Round 2
// 882.034 us; speedup vs baseline: 1.3147x; 1.3147x over previous
//
#include <hip/hip_runtime.h>
#include <hip/hip_bf16.h>
#include <math.h>

#define NN 50000
#define NE 400000
#define DIM 64
#define HEADS 4
#define SIC 0.5f

__device__ __forceinline__ float bf_lo(unsigned u) { return __uint_as_float(u << 16); }
__device__ __forceinline__ float bf_hi(unsigned u) { return __uint_as_float(u & 0xffff0000u); }

__device__ __forceinline__ unsigned pack_bf16c(float re, float im) {
    __hip_bfloat16 r = __float2bfloat16(re);
    __hip_bfloat16 i = __float2bfloat16(im);
    unsigned lo = *(unsigned short*)&r;
    unsigned hi = *(unsigned short*)&i;
    return lo | (hi << 16);
}

// ---------------- K0: transpose W,Q into [m][i][o] interleaved complex ----------------
__global__ void k0_transpose(const float* __restrict__ Wre, const float* __restrict__ Wim,
                             const float* __restrict__ Qre, const float* __restrict__ Qim,
                             float2* __restrict__ WTw, float2* __restrict__ WTq) {
    int tid = blockIdx.x * blockDim.x + threadIdx.x;
    if (tid >= HEADS * DIM * DIM) return;
    int m = tid >> 12;            // tid = m*4096 + o*64 + i
    int rem = tid & 4095;
    int o = rem >> 6, i = rem & 63;
    int didx = (m * DIM + i) * DIM + o;
    WTw[didx] = make_float2(Wre[tid], Wim[tid]);
    WTq[didx] = make_float2(Qre[tid], Qim[tid]);
}

// ---------------- K1: per-node Wh (bf16-packed out), Qh, t = Qh^H h, norm2 ----------------
__global__ __launch_bounds__(256) void k1_precompute(
    const float* __restrict__ h_re, const float* __restrict__ h_im,
    const float2* __restrict__ WTw, const float2* __restrict__ WTq,
    unsigned* __restrict__ Whb, float2* __restrict__ Qh,
    float2* __restrict__ t_out, float* __restrict__ norm2_out) {
    __shared__ float2 h_lds[8][DIM];
    int nbase = blockIdx.x * 8;
    int t = threadIdx.x;
    for (int k = t; k < 8 * DIM; k += 256) {
        int nb = k >> 6, d = k & 63;
        int n = nbase + nb;
        float2 v = make_float2(0.f, 0.f);
        if (n < NN) v = make_float2(h_re[n * DIM + d], h_im[n * DIM + d]);
        h_lds[nb][d] = v;
    }
    __syncthreads();
    int wave = t >> 6;   // head
    int lane = t & 63;   // output dim
    float2 accW[8], accQ[8];
#pragma unroll
    for (int nb = 0; nb < 8; ++nb) { accW[nb] = make_float2(0, 0); accQ[nb] = make_float2(0, 0); }
    const float2* wtw = WTw + wave * DIM * DIM;
    const float2* wtq = WTq + wave * DIM * DIM;
    for (int i = 0; i < DIM; ++i) {
        float2 w1 = wtw[i * DIM + lane];
        float2 q1 = wtq[i * DIM + lane];
#pragma unroll
        for (int nb = 0; nb < 8; ++nb) {
            float2 hv = h_lds[nb][i];
            accW[nb].x += hv.x * w1.x - hv.y * w1.y;
            accW[nb].y += hv.x * w1.y + hv.y * w1.x;
            accQ[nb].x += hv.x * q1.x - hv.y * q1.y;
            accQ[nb].y += hv.x * q1.y + hv.y * q1.x;
        }
    }
    float tv[16];
#pragma unroll
    for (int nb = 0; nb < 8; ++nb) {
        float2 hv = h_lds[nb][lane];
        tv[2 * nb]     = accQ[nb].x * hv.x + accQ[nb].y * hv.y;
        tv[2 * nb + 1] = accQ[nb].x * hv.y - accQ[nb].y * hv.x;
    }
    for (int off = 32; off; off >>= 1) {
#pragma unroll
        for (int k = 0; k < 16; ++k) tv[k] += __shfl_xor(tv[k], off, 64);
    }
#pragma unroll
    for (int nb = 0; nb < 8; ++nb) {
        int n = nbase + nb;
        if (n < NN) {
            Whb[(n * HEADS + wave) * DIM + lane] = pack_bf16c(accW[nb].x, accW[nb].y);
            Qh[(n * HEADS + wave) * DIM + lane] = accQ[nb];
            if (lane == 0) t_out[n * HEADS + wave] = make_float2(tv[2 * nb], tv[2 * nb + 1]);
        }
    }
    if (wave == 0) {
        float nv[8];
#pragma unroll
        for (int nb = 0; nb < 8; ++nb) { float2 hv = h_lds[nb][lane]; nv[nb] = hv.x * hv.x + hv.y * hv.y; }
        for (int off = 32; off; off >>= 1) {
#pragma unroll
            for (int k = 0; k < 8; ++k) nv[k] += __shfl_xor(nv[k], off, 64);
        }
        if (lane == 0) {
#pragma unroll
            for (int nb = 0; nb < 8; ++nb) { int n = nbase + nb; if (n < NN) norm2_out[n] = fmaxf(nv[nb], 1e-6f); }
        }
    }
}

// ---------------- CSR build ----------------
__global__ void k2a_count(const int* __restrict__ dst, int* __restrict__ counts) {
    int e = blockIdx.x * blockDim.x + threadIdx.x;
    if (e < NE) atomicAdd(&counts[dst[e]], 1);
}

__global__ __launch_bounds__(1024) void k2b_scan(const int* __restrict__ counts,
                                                 int* __restrict__ row_ptr, int* __restrict__ cursor) {
    __shared__ int buf[1024];
    int t = threadIdx.x;
    const int CH = (NN + 1023) / 1024;  // 49
    int i0 = t * CH;
    int i1 = min(i0 + CH, NN);
    int sum = 0;
    for (int i = i0; i < i1; ++i) sum += counts[i];
    buf[t] = sum;
    __syncthreads();
    for (int off = 1; off < 1024; off <<= 1) {
        int x = 0;
        if (t >= off) x = buf[t - off];
        __syncthreads();
        buf[t] += x;
        __syncthreads();
    }
    int run = buf[t] - sum;   // exclusive prefix of this chunk
    for (int i = i0; i < i1; ++i) { row_ptr[i] = run; cursor[i] = run; run += counts[i]; }
    if (t == 1023) row_ptr[NN] = buf[1023];
}

__global__ void k2c_fill(const int* __restrict__ src, const int* __restrict__ dst,
                         int* __restrict__ cursor, int* __restrict__ sorted_src) {
    int e = blockIdx.x * blockDim.x + threadIdx.x;
    if (e < NE) {
        int pos = atomicAdd(&cursor[dst[e]], 1);
        sorted_src[pos] = src[e];
    }
}

// ---------------- K_main: wave per node, 16-lane group per head, 4 dims/lane ----------------
__global__ __launch_bounds__(256) void k_main(
    const float* __restrict__ h_re, const float* __restrict__ h_im,
    const uint4* __restrict__ Whb, float2* __restrict__ Qh_S /* read Qh, write S in place */,
    const float2* __restrict__ t_in, const float* __restrict__ norm2_in,
    const int* __restrict__ row_ptr, const int* __restrict__ sorted_src,
    float2* __restrict__ T_out) {
    int wave = threadIdx.x >> 6;
    int lane = threadIdx.x & 63;
    int g = lane >> 4;          // head
    int l = lane & 15;          // dim block
    int n = blockIdx.x * 4 + wave;
    if (n >= NN) return;
    int d0 = l * 4;
    float hre[4], him[4], qre[4], qim[4];
    {
        float4 a = *(const float4*)(h_re + n * DIM + d0);
        float4 b = *(const float4*)(h_im + n * DIM + d0);
        hre[0] = a.x; hre[1] = a.y; hre[2] = a.z; hre[3] = a.w;
        him[0] = b.x; him[1] = b.y; him[2] = b.z; him[3] = b.w;
        const float* qp = (const float*)(Qh_S + (n * HEADS + g) * DIM + d0);
        float4 qa = *(const float4*)qp;
        float4 qb = *(const float4*)(qp + 4);
        qre[0] = qa.x; qim[0] = qa.y; qre[1] = qa.z; qim[1] = qa.w;
        qre[2] = qb.x; qim[2] = qb.y; qre[3] = qb.z; qim[3] = qb.w;
    }
    float2 tnm = t_in[n * HEADS + g];
    float inv_n2 = 1.0f / norm2_in[n];
    int beg = row_ptr[n], end = row_ptr[n + 1];
    float m_run = -1e30f, l_run = 0.f;
    float Sr[4] = {0, 0, 0, 0}, Si[4] = {0, 0, 0, 0};
    float Tr = 0.f, Ti = 0.f;
    float4 pre = make_float4(0, 0, 0, 0), pim = make_float4(0, 0, 0, 0);
    uint4 pwh = make_uint4(0, 0, 0, 0);
    if (beg < end) {
        int s = sorted_src[beg];
        pre = *(const float4*)(h_re + s * DIM + d0);
        pim = *(const float4*)(h_im + s * DIM + d0);
        pwh = Whb[(s * HEADS + g) * 16 + l];
    }
    for (int pos = beg; pos < end; ++pos) {
        float csr[4] = {pre.x, pre.y, pre.z, pre.w};
        float csi[4] = {pim.x, pim.y, pim.z, pim.w};
        uint4 cw = pwh;
        if (pos + 1 < end) {
            int s2 = sorted_src[pos + 1];
            pre = *(const float4*)(h_re + s2 * DIM + d0);
            pim = *(const float4*)(h_im + s2 * DIM + d0);
            pwh = Whb[(s2 * HEADS + g) * 16 + l];
        }
        float wr[4], wi[4];
        wr[0] = bf_lo(cw.x); wi[0] = bf_hi(cw.x);
        wr[1] = bf_lo(cw.y); wi[1] = bf_hi(cw.y);
        wr[2] = bf_lo(cw.z); wi[2] = bf_hi(cw.z);
        wr[3] = bf_lo(cw.w); wi[3] = bf_hi(cw.w);
        float r0 = 0, r1 = 0, r2 = 0, r3 = 0, r4 = 0;
#pragma unroll
        for (int j = 0; j < 4; ++j) {
            r0 += hre[j] * wr[j] + him[j] * wi[j];     // conj(hd).Wh re
            r1 += hre[j] * wi[j] - him[j] * wr[j];     // conj(hd).Wh im
            r2 += qre[j] * wr[j] + qim[j] * wi[j];     // conj(Qh).Wh re
            r3 += qre[j] * wi[j] - qim[j] * wr[j];     // conj(Qh).Wh im
            r4 += hre[j] * csr[j];                     // h_re[dst].h_re[src]
        }
#pragma unroll
        for (int off = 1; off < 16; off <<= 1) {
            r0 += __shfl_xor(r0, off, 64);
            r1 += __shfl_xor(r1, off, 64);
            r2 += __shfl_xor(r2, off, 64);
            r3 += __shfl_xor(r3, off, 64);
            r4 += __shfl_xor(r4, off, 64);
        }
        float sg = (r4 > 0.f) ? 1.f : ((r4 < 0.f) ? 0.f : 0.5f);
        float cre = SIC * r0 * inv_n2;
        float cim = SIC * r1 * inv_n2;
        float sre = r2 - (cre * tnm.x - cim * tnm.y);
        float sim_ = r3 - (cre * tnm.y + cim * tnm.x);
        float logit = sqrtf(sre * sre + sim_ * sim_) * 0.125f;  // GAMMA/sqrt(D)
        float mnew = fmaxf(m_run, logit);
        float f = __expf(m_run - mnew);    // first edge: exp(-1e30) = 0
        float ex = __expf(logit - mnew);
        float w = ex * sg;
        l_run = l_run * f + ex;
#pragma unroll
        for (int j = 0; j < 4; ++j) {
            Sr[j] = Sr[j] * f + w * csr[j];
            Si[j] = Si[j] * f + w * csi[j];
        }
        Tr = Tr * f + w * cre;
        Ti = Ti * f + w * cim;
        m_run = mnew;
    }
    float inv = 1.0f / (l_run + 1e-16f);
    float* op = (float*)(Qh_S + (n * HEADS + g) * DIM + d0);
    *(float4*)op       = make_float4(Sr[0] * inv, Si[0] * inv, Sr[1] * inv, Si[1] * inv);
    *(float4*)(op + 4) = make_float4(Sr[2] * inv, Si[2] * inv, Sr[3] * inv, Si[3] * inv);
    if (l == 0) T_out[n * HEADS + g] = make_float2(Tr * inv, Ti * inv);
}

// ---------------- K5: updates = sum_m Wm@S - gate*Tsum*h; NodeNorm; ModReLU ----------------
__global__ __launch_bounds__(256) void k5_finish(
    const float* __restrict__ h_re, const float* __restrict__ h_im,
    const float2* __restrict__ S_in, const float2* __restrict__ T_in,
    const float2* __restrict__ WTw,
    const float* __restrict__ gate_raw, const float* __restrict__ modrelu_b,
    float2* __restrict__ out) {
    __shared__ float2 S_lds[32][HEADS][DIM];  // 64 KiB
    int t = threadIdx.x;
    int nbase = blockIdx.x * 32;
    for (int k = t; k < 32 * HEADS * DIM; k += 256) {
        long gidx = (long)nbase * HEADS * DIM + k;
        float2 v = make_float2(0, 0);
        if (gidx < (long)NN * HEADS * DIM) v = S_in[gidx];
        ((float2*)S_lds)[k] = v;
    }
    __syncthreads();
    int wave = t >> 6, lane = t & 63;
    float gate = 1.0f / (1.0f + expf(-gate_raw[0]));
    float b = modrelu_b[lane];
    float2 U[8];
#pragma unroll
    for (int nb = 0; nb < 8; ++nb) U[nb] = make_float2(0, 0);
    for (int m = 0; m < HEADS; ++m) {
        const float2* wt = WTw + m * DIM * DIM;
        for (int i = 0; i < DIM; ++i) {
            float2 w1 = wt[i * DIM + lane];
#pragma unroll
            for (int nb = 0; nb < 8; ++nb) {
                float2 s = S_lds[wave * 8 + nb][m][i];
                U[nb].x += s.x * w1.x - s.y * w1.y;
                U[nb].y += s.x * w1.y + s.y * w1.x;
            }
        }
    }
#pragma unroll
    for (int nb = 0; nb < 8; ++nb) {
        int nl = wave * 8 + nb;
        int n = nbase + nl;
        float2 Ts = make_float2(0, 0);
        float2 hv = make_float2(0, 0);
        if (n < NN) {
#pragma unroll
            for (int m = 0; m < HEADS; ++m) { float2 tv = T_in[n * HEADS + m]; Ts.x += tv.x; Ts.y += tv.y; }
            hv = make_float2(h_re[n * DIM + lane], h_im[n * DIM + lane]);
        }
        float hre = hv.x + U[nb].x - gate * (Ts.x * hv.x - Ts.y * hv.y);
        float him = hv.y + U[nb].y - gate * (Ts.x * hv.y + Ts.y * hv.x);
        float r4[4] = {hre, him, hre * hre, him * him};
        for (int off = 32; off; off >>= 1) {
#pragma unroll
            for (int k = 0; k < 4; ++k) r4[k] += __shfl_xor(r4[k], off, 64);
        }
        float mean_r = r4[0] * (1.f / DIM), mean_i = r4[1] * (1.f / DIM);
        float var_r = (r4[2] - DIM * mean_r * mean_r) * (1.f / (DIM - 1));
        float var_i = (r4[3] - DIM * mean_i * mean_i) * (1.f / (DIM - 1));
        float std_r = fmaxf(sqrtf(fmaxf(var_r, 0.f)), 1e-5f);
        float std_i = fmaxf(sqrtf(fmaxf(var_i, 0.f)), 1e-5f);
        float xr = (hre - mean_r) / std_r;
        float xi = (him - mean_i) / std_i;
        float mag = fmaxf(sqrtf(xr * xr + xi * xi), 1e-6f);
        float gg = fmaxf(mag + b, 0.f);
        float sc = gg / mag;
        if (n < NN) out[n * DIM + lane] = make_float2(xr * sc, xi * sc);
    }
}

extern "C" void kernel_launch(void* const* d_in, const int* in_sizes, int n_in,
                              void* d_out, int out_size, void* d_ws, size_t ws_size,
                              hipStream_t stream) {
    const float* h_re = (const float*)d_in[0];
    const float* h_im = (const float*)d_in[1];
    const float* W_re = (const float*)d_in[2];
    const float* W_im = (const float*)d_in[3];
    const float* Q_re = (const float*)d_in[4];
    const float* Q_im = (const float*)d_in[5];
    const float* gate_raw = (const float*)d_in[6];
    const float* b = (const float*)d_in[7];
    const int* src = (const int*)d_in[8];
    const int* dst = (const int*)d_in[9];

    char* ws = (char*)d_ws;
    size_t off = 0;
    auto alloc = [&](size_t bytes) {
        void* p = ws + off;
        off = (off + bytes + 255) & ~(size_t)255;
        return p;
    };
    float2* WTw = (float2*)alloc((size_t)HEADS * DIM * DIM * sizeof(float2));
    float2* WTq = (float2*)alloc((size_t)HEADS * DIM * DIM * sizeof(float2));
    unsigned* Whb = (unsigned*)alloc((size_t)NN * HEADS * DIM * sizeof(unsigned));
    float2* Qh = (float2*)alloc((size_t)NN * HEADS * DIM * sizeof(float2));  // reused as S
    float2* t_buf = (float2*)alloc((size_t)NN * HEADS * sizeof(float2));
    float* norm2 = (float*)alloc((size_t)NN * sizeof(float));
    float2* T_buf = (float2*)alloc((size_t)NN * HEADS * sizeof(float2));
    int* counts = (int*)alloc((size_t)NN * sizeof(int));
    int* row_ptr = (int*)alloc((size_t)(NN + 1) * sizeof(int));
    int* cursor = (int*)alloc((size_t)NN * sizeof(int));
    int* sorted_src = (int*)alloc((size_t)NE * sizeof(int));

    hipMemsetAsync(counts, 0, (size_t)NN * sizeof(int), stream);
    k0_transpose<<<(HEADS * DIM * DIM + 255) / 256, 256, 0, stream>>>(W_re, W_im, Q_re, Q_im, WTw, WTq);
    k1_precompute<<<(NN + 7) / 8, 256, 0, stream>>>(h_re, h_im, WTw, WTq, Whb, Qh, t_buf, norm2);
    k2a_count<<<(NE + 255) / 256, 256, 0, stream>>>(dst, counts);
    k2b_scan<<<1, 1024, 0, stream>>>(counts, row_ptr, cursor);
    k2c_fill<<<(NE + 255) / 256, 256, 0, stream>>>(src, dst, cursor, sorted_src);
    k_main<<<(NN + 3) / 4, 256, 0, stream>>>(h_re, h_im, (const uint4*)Whb, Qh, t_buf, norm2, row_ptr, sorted_src, T_buf);
    k5_finish<<<(NN + 31) / 32, 256, 0, stream>>>(h_re, h_im, Qh, T_buf, WTw, gate_raw, b, (float2*)d_out);
}

// Round 3
// 779.494 us; speedup vs baseline: 1.4876x; 1.1315x over previous
//
#include <hip/hip_runtime.h>
#include <hip/hip_bf16.h>
#include <math.h>

#define NN 50000
#define NE 400000
#define DIM 64
#define HEADS 4
#define SIC 0.5f

typedef __bf16 bf16x8 __attribute__((ext_vector_type(8)));
typedef float f32x4 __attribute__((ext_vector_type(4)));

__device__ __forceinline__ float bf_lo(unsigned u) { return __uint_as_float(u << 16); }
__device__ __forceinline__ float bf_hi(unsigned u) { return __uint_as_float(u & 0xffff0000u); }

__device__ __forceinline__ unsigned pack_bf16c(float re, float im) {
    __bf16 r = (__bf16)re, i = (__bf16)im;
    unsigned short lo = __builtin_bit_cast(unsigned short, r);
    unsigned short hi = __builtin_bit_cast(unsigned short, i);
    return (unsigned)lo | ((unsigned)hi << 16);
}

// ---------------- K0a: WTw float2 [m][i][o] for k5 ----------------
__global__ void k0_transpose(const float* __restrict__ Wre, const float* __restrict__ Wim,
                             float2* __restrict__ WTw) {
    int tid = blockIdx.x * blockDim.x + threadIdx.x;
    if (tid >= HEADS * DIM * DIM) return;
    int m = tid >> 12;            // tid = m*4096 + o*64 + i
    int rem = tid & 4095;
    int o = rem >> 6, i = rem & 63;
    int didx = (m * DIM + i) * DIM + o;
    WTw[didx] = make_float2(Wre[tid], Wim[tid]);
}

// ---------------- K0b: build B_t (transposed, bf16 hi/lo) for the k1 GEMM --------------
// B[k][c]: c = m*256 + mat*128 + comp*64 + o ; k<64 -> real input i=k, k>=64 -> imag i=k-64
// stored transposed: Bt[c][k], [1024][128] bf16
__global__ void k0b_build(const float* __restrict__ Wre, const float* __restrict__ Wim,
                          const float* __restrict__ Qre, const float* __restrict__ Qim,
                          __bf16* __restrict__ Bt_hi, __bf16* __restrict__ Bt_lo) {
    int tid = blockIdx.x * blockDim.x + threadIdx.x;   // c*128 + k
    if (tid >= 1024 * 128) return;
    int c = tid >> 7, k = tid & 127;
    int mh = c >> 8, cm = c & 255;
    int mat = cm >> 7, comp = (cm >> 6) & 1, o = cm & 63;
    int part = k >> 6, i = k & 63;
    const float* Mre = mat ? Qre : Wre;
    const float* Mim = mat ? Qim : Wim;
    int widx = (mh * DIM + o) * DIM + i;
    float v;
    if (comp == 0) v = part ? -Mim[widx] : Mre[widx];
    else           v = part ?  Mre[widx] : Mim[widx];
    __bf16 hi = (__bf16)v;
    Bt_hi[tid] = hi;
    Bt_lo[tid] = (__bf16)(v - (float)hi);
}

// ---------------- K1: MFMA GEMM  [64 nodes x 256 cols(one head)] per workgroup --------
// A[n][k] = k<64 ? h_re[n][k] : h_im[n][k-64], split hi/lo bf16.
// C = Ahi*Bhi + Alo*Bhi + Ahi*Blo  (~f32 precision)
__global__ __launch_bounds__(256) void k1_mfma(
    const float* __restrict__ h_re, const float* __restrict__ h_im,
    const __bf16* __restrict__ Bt_hi, const __bf16* __restrict__ Bt_lo,
    unsigned* __restrict__ Whb, float2* __restrict__ Qh) {
    int w = threadIdx.x >> 6, l = threadIdx.x & 63;
    int mh = blockIdx.x & 3, rb = blockIdx.x >> 2;
    int n0 = rb * 64 + w * 16;
    if (n0 >= NN) return;                       // 50000 = 781*64 + 16: tail block keeps wave 0 only
    int r = l & 15, g = l >> 4;
    int node = n0 + r;

    // A fragments for all 4 K-chunks (k-slice: ch*32 + g*8 .. +8), hi & lo
    bf16x8 Ahi[4], Alo[4];
#pragma unroll
    for (int ch = 0; ch < 4; ++ch) {
        int K = ch * 32 + g * 8;
        const float* hp = (K & 64) ? h_im : h_re;
        const float4* p = (const float4*)(hp + node * DIM + (K & 63));
        float4 a = p[0], b = p[1];
        float v[8] = {a.x, a.y, a.z, a.w, b.x, b.y, b.z, b.w};
#pragma unroll
        for (int j = 0; j < 8; ++j) {
            __bf16 hi = (__bf16)v[j];
            Ahi[ch][j] = hi;
            Alo[ch][j] = (__bf16)(v[j] - (float)hi);
        }
    }

    f32x4 acc[16];
#pragma unroll
    for (int t = 0; t < 16; ++t) acc[t] = {0.f, 0.f, 0.f, 0.f};

    // B fragment base: c = mh*256 + nt*16 + r ; k = ch*32 + g*8
    const __bf16* bh_base = Bt_hi + (mh * 256 + r) * 128 + g * 8;
    const __bf16* bl_base = Bt_lo + (mh * 256 + r) * 128 + g * 8;

    bf16x8 bh = *(const bf16x8*)(bh_base);
    bf16x8 bl = *(const bf16x8*)(bl_base);
#pragma unroll
    for (int ch = 0; ch < 4; ++ch) {
        bf16x8 ah = Ahi[ch], al = Alo[ch];
#pragma unroll
        for (int nt = 0; nt < 16; ++nt) {
            bf16x8 bhc = bh, blc = bl;
            int nidx = ch * 16 + nt + 1;
            if (nidx < 64) {
                int nch = nidx >> 4, nnt = nidx & 15;
                bh = *(const bf16x8*)(bh_base + nnt * 2048 + nch * 32);
                bl = *(const bf16x8*)(bl_base + nnt * 2048 + nch * 32);
            }
            acc[nt] = __builtin_amdgcn_mfma_f32_16x16x32_bf16(ah, bhc, acc[nt], 0, 0, 0);
            acc[nt] = __builtin_amdgcn_mfma_f32_16x16x32_bf16(al, bhc, acc[nt], 0, 0, 0);
            acc[nt] = __builtin_amdgcn_mfma_f32_16x16x32_bf16(ah, blc, acc[nt], 0, 0, 0);
        }
    }

    // epilogue: C/D layout col = lane&15, row = g*4 + j (m89-verified)
    // tiles 0-3: Wre, 4-7: Wim, 8-11: Qre, 12-15: Qim ; o = q*16 + r
#pragma unroll
    for (int q = 0; q < 4; ++q) {
        f32x4 wre = acc[q], wim = acc[q + 4];
        f32x4 qre = acc[8 + q], qim = acc[12 + q];
        int o = q * 16 + r;
#pragma unroll
        for (int j = 0; j < 4; ++j) {
            int n = n0 + g * 4 + j;
            Whb[(n * HEADS + mh) * DIM + o] = pack_bf16c(wre[j], wim[j]);
            Qh[(n * HEADS + mh) * DIM + o] = make_float2(qre[j], qim[j]);
        }
    }
}

// ---------------- CSR build ----------------
__global__ void k2a_count(const int* __restrict__ dst, int* __restrict__ counts) {
    int e = blockIdx.x * blockDim.x + threadIdx.x;
    if (e < NE) atomicAdd(&counts[dst[e]], 1);
}

__global__ __launch_bounds__(1024) void k2b_scan(const int* __restrict__ counts,
                                                 int* __restrict__ row_ptr, int* __restrict__ cursor) {
    __shared__ int buf[1024];
    int t = threadIdx.x;
    const int CH = (NN + 1023) / 1024;  // 49
    int i0 = t * CH;
    int i1 = min(i0 + CH, NN);
    int sum = 0;
    for (int i = i0; i < i1; ++i) sum += counts[i];
    buf[t] = sum;
    __syncthreads();
    for (int off = 1; off < 1024; off <<= 1) {
        int x = 0;
        if (t >= off) x = buf[t - off];
        __syncthreads();
        buf[t] += x;
        __syncthreads();
    }
    int run = buf[t] - sum;   // exclusive prefix of this chunk
    for (int i = i0; i < i1; ++i) { row_ptr[i] = run; cursor[i] = run; run += counts[i]; }
    if (t == 1023) row_ptr[NN] = buf[1023];
}

__global__ void k2c_fill(const int* __restrict__ src, const int* __restrict__ dst,
                         int* __restrict__ cursor, int* __restrict__ sorted_src) {
    int e = blockIdx.x * blockDim.x + threadIdx.x;
    if (e < NE) {
        int pos = atomicAdd(&cursor[dst[e]], 1);
        sorted_src[pos] = src[e];
    }
}

// ---------------- K_main: wave per node, 16-lane group per head, 4 dims/lane ----------------
__global__ __launch_bounds__(256) void k_main(
    const float* __restrict__ h_re, const float* __restrict__ h_im,
    const uint4* __restrict__ Whb, float2* __restrict__ Qh_S /* read Qh, write S in place */,
    const int* __restrict__ row_ptr, const int* __restrict__ sorted_src,
    float2* __restrict__ T_out) {
    int wave = threadIdx.x >> 6;
    int lane = threadIdx.x & 63;
    int g = lane >> 4;          // head
    int l = lane & 15;          // dim block
    int n = blockIdx.x * 4 + wave;
    if (n >= NN) return;
    int d0 = l * 4;
    float hre[4], him[4], qre[4], qim[4];
    {
        float4 a = *(const float4*)(h_re + n * DIM + d0);
        float4 b = *(const float4*)(h_im + n * DIM + d0);
        hre[0] = a.x; hre[1] = a.y; hre[2] = a.z; hre[3] = a.w;
        him[0] = b.x; him[1] = b.y; him[2] = b.z; him[3] = b.w;
        const float* qp = (const float*)(Qh_S + (n * HEADS + g) * DIM + d0);
        float4 qa = *(const float4*)qp;
        float4 qb = *(const float4*)(qp + 4);
        qre[0] = qa.x; qim[0] = qa.y; qre[1] = qa.z; qim[1] = qa.w;
        qre[2] = qb.x; qim[2] = qb.y; qre[3] = qb.z; qim[3] = qb.w;
    }
    // t[n][m] = conj(Qh).h  and norm2 = |h|^2, reduced over the 16-lane group
    float tr = 0.f, ti = 0.f, nr = 0.f;
#pragma unroll
    for (int j = 0; j < 4; ++j) {
        tr += qre[j] * hre[j] + qim[j] * him[j];
        ti += qre[j] * him[j] - qim[j] * hre[j];
        nr += hre[j] * hre[j] + him[j] * him[j];
    }
#pragma unroll
    for (int off = 1; off < 16; off <<= 1) {
        tr += __shfl_xor(tr, off, 64);
        ti += __shfl_xor(ti, off, 64);
        nr += __shfl_xor(nr, off, 64);
    }
    float2 tnm = make_float2(tr, ti);
    float inv_n2 = 1.0f / fmaxf(nr, 1e-6f);

    int beg = row_ptr[n], end = row_ptr[n + 1];
    float m_run = -1e30f, l_run = 0.f;
    float Sr[4] = {0, 0, 0, 0}, Si[4] = {0, 0, 0, 0};
    float Tr = 0.f, Ti = 0.f;
    float4 pre = make_float4(0, 0, 0, 0), pim = make_float4(0, 0, 0, 0);
    uint4 pwh = make_uint4(0, 0, 0, 0);
    if (beg < end) {
        int s = sorted_src[beg];
        pre = *(const float4*)(h_re + s * DIM + d0);
        pim = *(const float4*)(h_im + s * DIM + d0);
        pwh = Whb[(s * HEADS + g) * 16 + l];
    }
    for (int pos = beg; pos < end; ++pos) {
        float csr[4] = {pre.x, pre.y, pre.z, pre.w};
        float csi[4] = {pim.x, pim.y, pim.z, pim.w};
        uint4 cw = pwh;
        if (pos + 1 < end) {
            int s2 = sorted_src[pos + 1];
            pre = *(const float4*)(h_re + s2 * DIM + d0);
            pim = *(const float4*)(h_im + s2 * DIM + d0);
            pwh = Whb[(s2 * HEADS + g) * 16 + l];
        }
        float wr[4], wi[4];
        wr[0] = bf_lo(cw.x); wi[0] = bf_hi(cw.x);
        wr[1] = bf_lo(cw.y); wi[1] = bf_hi(cw.y);
        wr[2] = bf_lo(cw.z); wi[2] = bf_hi(cw.z);
        wr[3] = bf_lo(cw.w); wi[3] = bf_hi(cw.w);
        float r0 = 0, r1 = 0, r2 = 0, r3 = 0, r4 = 0;
#pragma unroll
        for (int j = 0; j < 4; ++j) {
            r0 += hre[j] * wr[j] + him[j] * wi[j];     // conj(hd).Wh re
            r1 += hre[j] * wi[j] - him[j] * wr[j];     // conj(hd).Wh im
            r2 += qre[j] * wr[j] + qim[j] * wi[j];     // conj(Qh).Wh re
            r3 += qre[j] * wi[j] - qim[j] * wr[j];     // conj(Qh).Wh im
            r4 += hre[j] * csr[j];                     // h_re[dst].h_re[src]
        }
#pragma unroll
        for (int off = 1; off < 16; off <<= 1) {
            r0 += __shfl_xor(r0, off, 64);
            r1 += __shfl_xor(r1, off, 64);
            r2 += __shfl_xor(r2, off, 64);
            r3 += __shfl_xor(r3, off, 64);
            r4 += __shfl_xor(r4, off, 64);
        }
        float sg = (r4 > 0.f) ? 1.f : ((r4 < 0.f) ? 0.f : 0.5f);
        float cre = SIC * r0 * inv_n2;
        float cim = SIC * r1 * inv_n2;
        float sre = r2 - (cre * tnm.x - cim * tnm.y);
        float sim_ = r3 - (cre * tnm.y + cim * tnm.x);
        float logit = sqrtf(sre * sre + sim_ * sim_) * 0.125f;  // GAMMA/sqrt(D)
        float mnew = fmaxf(m_run, logit);
        float f = __expf(m_run - mnew);    // first edge: exp(-1e30) = 0
        float ex = __expf(logit - mnew);
        float w = ex * sg;
        l_run = l_run * f + ex;
#pragma unroll
        for (int j = 0; j < 4; ++j) {
            Sr[j] = Sr[j] * f + w * csr[j];
            Si[j] = Si[j] * f + w * csi[j];
        }
        Tr = Tr * f + w * cre;
        Ti = Ti * f + w * cim;
        m_run = mnew;
    }
    float inv = 1.0f / (l_run + 1e-16f);
    float* op = (float*)(Qh_S + (n * HEADS + g) * DIM + d0);
    *(float4*)op       = make_float4(Sr[0] * inv, Si[0] * inv, Sr[1] * inv, Si[1] * inv);
    *(float4*)(op + 4) = make_float4(Sr[2] * inv, Si[2] * inv, Sr[3] * inv, Si[3] * inv);
    if (l == 0) T_out[n * HEADS + g] = make_float2(Tr * inv, Ti * inv);
}

// ---------------- K5: updates = sum_m Wm@S - gate*Tsum*h; NodeNorm; ModReLU ----------------
__global__ __launch_bounds__(256) void k5_finish(
    const float* __restrict__ h_re, const float* __restrict__ h_im,
    const float2* __restrict__ S_in, const float2* __restrict__ T_in,
    const float2* __restrict__ WTw,
    const float* __restrict__ gate_raw, const float* __restrict__ modrelu_b,
    float2* __restrict__ out) {
    __shared__ float2 S_lds[32][HEADS][DIM];  // 64 KiB
    int t = threadIdx.x;
    int nbase = blockIdx.x * 32;
    for (int k = t; k < 32 * HEADS * DIM; k += 256) {
        long gidx = (long)nbase * HEADS * DIM + k;
        float2 v = make_float2(0, 0);
        if (gidx < (long)NN * HEADS * DIM) v = S_in[gidx];
        ((float2*)S_lds)[k] = v;
    }
    __syncthreads();
    int wave = t >> 6, lane = t & 63;
    float gate = 1.0f / (1.0f + expf(-gate_raw[0]));
    float b = modrelu_b[lane];
    float2 U[8];
#pragma unroll
    for (int nb = 0; nb < 8; ++nb) U[nb] = make_float2(0, 0);
    for (int m = 0; m < HEADS; ++m) {
        const float2* wt = WTw + m * DIM * DIM;
        for (int i = 0; i < DIM; ++i) {
            float2 w1 = wt[i * DIM + lane];
#pragma unroll
            for (int nb = 0; nb < 8; ++nb) {
                float2 s = S_lds[wave * 8 + nb][m][i];
                U[nb].x += s.x * w1.x - s.y * w1.y;
                U[nb].y += s.x * w1.y + s.y * w1.x;
            }
        }
    }
#pragma unroll
    for (int nb = 0; nb < 8; ++nb) {
        int nl = wave * 8 + nb;
        int n = nbase + nl;
        float2 Ts = make_float2(0, 0);
        float2 hv = make_float2(0, 0);
        if (n < NN) {
#pragma unroll
            for (int m = 0; m < HEADS; ++m) { float2 tv = T_in[n * HEADS + m]; Ts.x += tv.x; Ts.y += tv.y; }
            hv = make_float2(h_re[n * DIM + lane], h_im[n * DIM + lane]);
        }
        float hre = hv.x + U[nb].x - gate * (Ts.x * hv.x - Ts.y * hv.y);
        float him = hv.y + U[nb].y - gate * (Ts.x * hv.y + Ts.y * hv.x);
        float r4[4] = {hre, him, hre * hre, him * him};
        for (int off = 32; off; off >>= 1) {
#pragma unroll
            for (int k = 0; k < 4; ++k) r4[k] += __shfl_xor(r4[k], off, 64);
        }
        float mean_r = r4[0] * (1.f / DIM), mean_i = r4[1] * (1.f / DIM);
        float var_r = (r4[2] - DIM * mean_r * mean_r) * (1.f / (DIM - 1));
        float var_i = (r4[3] - DIM * mean_i * mean_i) * (1.f / (DIM - 1));
        float std_r = fmaxf(sqrtf(fmaxf(var_r, 0.f)), 1e-5f);
        float std_i = fmaxf(sqrtf(fmaxf(var_i, 0.f)), 1e-5f);
        float xr = (hre - mean_r) / std_r;
        float xi = (him - mean_i) / std_i;
        float mag = fmaxf(sqrtf(xr * xr + xi * xi), 1e-6f);
        float gg = fmaxf(mag + b, 0.f);
        float sc = gg / mag;
        if (n < NN) out[n * DIM + lane] = make_float2(xr * sc, xi * sc);
    }
}

extern "C" void kernel_launch(void* const* d_in, const int* in_sizes, int n_in,
                              void* d_out, int out_size, void* d_ws, size_t ws_size,
                              hipStream_t stream) {
    const float* h_re = (const float*)d_in[0];
    const float* h_im = (const float*)d_in[1];
    const float* W_re = (const float*)d_in[2];
    const float* W_im = (const float*)d_in[3];
    const float* Q_re = (const float*)d_in[4];
    const float* Q_im = (const float*)d_in[5];
    const float* gate_raw = (const float*)d_in[6];
    const float* b = (const float*)d_in[7];
    const int* src = (const int*)d_in[8];
    const int* dst = (const int*)d_in[9];

    char* ws = (char*)d_ws;
    size_t off = 0;
    auto alloc = [&](size_t bytes) {
        void* p = ws + off;
        off = (off + bytes + 255) & ~(size_t)255;
        return p;
    };
    float2* WTw = (float2*)alloc((size_t)HEADS * DIM * DIM * sizeof(float2));
    __bf16* Bt_hi = (__bf16*)alloc((size_t)1024 * 128 * sizeof(__bf16));
    __bf16* Bt_lo = (__bf16*)alloc((size_t)1024 * 128 * sizeof(__bf16));
    unsigned* Whb = (unsigned*)alloc((size_t)NN * HEADS * DIM * sizeof(unsigned));
    float2* Qh = (float2*)alloc((size_t)NN * HEADS * DIM * sizeof(float2));  // reused as S
    float2* T_buf = (float2*)alloc((size_t)NN * HEADS * sizeof(float2));
    int* counts = (int*)alloc((size_t)NN * sizeof(int));
    int* row_ptr = (int*)alloc((size_t)(NN + 1) * sizeof(int));
    int* cursor = (int*)alloc((size_t)NN * sizeof(int));
    int* sorted_src = (int*)alloc((size_t)NE * sizeof(int));

    hipMemsetAsync(counts, 0, (size_t)NN * sizeof(int), stream);
    k0_transpose<<<(HEADS * DIM * DIM + 255) / 256, 256, 0, stream>>>(W_re, W_im, WTw);
    k0b_build<<<(1024 * 128 + 255) / 256, 256, 0, stream>>>(W_re, W_im, Q_re, Q_im, Bt_hi, Bt_lo);
    k1_mfma<<<4 * ((NN + 63) / 64), 256, 0, stream>>>(h_re, h_im, Bt_hi, Bt_lo, Whb, Qh);
    k2a_count<<<(NE + 255) / 256, 256, 0, stream>>>(dst, counts);
    k2b_scan<<<1, 1024, 0, stream>>>(counts, row_ptr, cursor);
    k2c_fill<<<(NE + 255) / 256, 256, 0, stream>>>(src, dst, cursor, sorted_src);
    k_main<<<(NN + 3) / 4, 256, 0, stream>>>(h_re, h_im, (const uint4*)Whb, Qh, row_ptr, sorted_src, T_buf);
    k5_finish<<<(NN + 31) / 32, 256, 0, stream>>>(h_re, h_im, Qh, T_buf, WTw, gate_raw, b, (float2*)d_out);
}

// Round 4
// 651.923 us; speedup vs baseline: 1.7787x; 1.1957x over previous
//
#include <hip/hip_runtime.h>
#include <hip/hip_bf16.h>
#include <math.h>

#define NN 50000
#define NE 400000
#define DIM 64
#define HEADS 4
#define SIC 0.5f

typedef __bf16 bf16x8 __attribute__((ext_vector_type(8)));
typedef float f32x4 __attribute__((ext_vector_type(4)));

__device__ __forceinline__ float bf_lo(unsigned u) { return __uint_as_float(u << 16); }
__device__ __forceinline__ float bf_hi(unsigned u) { return __uint_as_float(u & 0xffff0000u); }

__device__ __forceinline__ unsigned pack_bf16c(float re, float im) {
    __bf16 r = (__bf16)re, i = (__bf16)im;
    unsigned short lo = __builtin_bit_cast(unsigned short, r);
    unsigned short hi = __builtin_bit_cast(unsigned short, i);
    return (unsigned)lo | ((unsigned)hi << 16);
}

// ---------------- K0b: build B_t (transposed, bf16 hi/lo) for the k1 GEMM --------------
// B[k][c]: c = m*256 + mat*128 + comp*64 + o ; k<64 -> real input i=k, k>=64 -> imag i=k-64
// stored transposed: Bt[c][k], [1024][128] bf16
__global__ void k0b_build(const float* __restrict__ Wre, const float* __restrict__ Wim,
                          const float* __restrict__ Qre, const float* __restrict__ Qim,
                          __bf16* __restrict__ Bt_hi, __bf16* __restrict__ Bt_lo) {
    int tid = blockIdx.x * blockDim.x + threadIdx.x;   // c*128 + k
    if (tid >= 1024 * 128) return;
    int c = tid >> 7, k = tid & 127;
    int mh = c >> 8, cm = c & 255;
    int mat = cm >> 7, comp = (cm >> 6) & 1, o = cm & 63;
    int part = k >> 6, i = k & 63;
    const float* Mre = mat ? Qre : Wre;
    const float* Mim = mat ? Qim : Wim;
    int widx = (mh * DIM + o) * DIM + i;
    float v;
    if (comp == 0) v = part ? -Mim[widx] : Mre[widx];
    else           v = part ?  Mre[widx] : Mim[widx];
    __bf16 hi = (__bf16)v;
    Bt_hi[tid] = hi;
    Bt_lo[tid] = (__bf16)(v - (float)hi);
}

// ---------------- K0c: build B2_t for the k5 GEMM --------------
// A row n = raw float stream of S[n]: k = m*128 + i*2 + cin  (cin: 0=re,1=im)
// C cols: c_out = comp_out*64 + o
// complex W*S: Ure = Wre*Sre - Wim*Sim ; Uim = Wim*Sre + Wre*Sim
// stored transposed: Bt2[c_out][k], [128][512] bf16
__global__ void k0c_build(const float* __restrict__ Wre, const float* __restrict__ Wim,
                          __bf16* __restrict__ Bt_hi, __bf16* __restrict__ Bt_lo) {
    int tid = blockIdx.x * blockDim.x + threadIdx.x;   // c_out*512 + k
    if (tid >= 128 * 512) return;
    int c_out = tid >> 9, k = tid & 511;
    int comp_out = c_out >> 6, o = c_out & 63;
    int m = k >> 7, cin = k & 1, i = (k >> 1) & 63;
    int widx = (m * DIM + o) * DIM + i;
    float v;
    if (cin == 0) v = comp_out ? Wim[widx] : Wre[widx];
    else          v = comp_out ? Wre[widx] : -Wim[widx];
    __bf16 hi = (__bf16)v;
    Bt_hi[tid] = hi;
    Bt_lo[tid] = (__bf16)(v - (float)hi);
}

// ---------------- K1: MFMA GEMM  [64 nodes x 256 cols(one head)] per workgroup --------
// A[n][k] = k<64 ? h_re[n][k] : h_im[n][k-64], split hi/lo bf16.
// C = Ahi*Bhi + Alo*Bhi + Ahi*Blo  (~f32 precision)
__global__ __launch_bounds__(256) void k1_mfma(
    const float* __restrict__ h_re, const float* __restrict__ h_im,
    const __bf16* __restrict__ Bt_hi, const __bf16* __restrict__ Bt_lo,
    unsigned* __restrict__ Whb, float2* __restrict__ Qh) {
    int w = threadIdx.x >> 6, l = threadIdx.x & 63;
    int mh = blockIdx.x & 3, rb = blockIdx.x >> 2;
    int n0 = rb * 64 + w * 16;
    if (n0 >= NN) return;                       // 50000 = 781*64 + 16: tail block keeps wave 0 only
    int r = l & 15, g = l >> 4;
    int node = n0 + r;

    // A fragments for all 4 K-chunks (k-slice: ch*32 + g*8 .. +8), hi & lo
    bf16x8 Ahi[4], Alo[4];
#pragma unroll
    for (int ch = 0; ch < 4; ++ch) {
        int K = ch * 32 + g * 8;
        const float* hp = (K & 64) ? h_im : h_re;
        const float4* p = (const float4*)(hp + node * DIM + (K & 63));
        float4 a = p[0], b = p[1];
        float v[8] = {a.x, a.y, a.z, a.w, b.x, b.y, b.z, b.w};
#pragma unroll
        for (int j = 0; j < 8; ++j) {
            __bf16 hi = (__bf16)v[j];
            Ahi[ch][j] = hi;
            Alo[ch][j] = (__bf16)(v[j] - (float)hi);
        }
    }

    f32x4 acc[16];
#pragma unroll
    for (int t = 0; t < 16; ++t) acc[t] = {0.f, 0.f, 0.f, 0.f};

    // B fragment base: c = mh*256 + nt*16 + r ; k = ch*32 + g*8
    const __bf16* bh_base = Bt_hi + (mh * 256 + r) * 128 + g * 8;
    const __bf16* bl_base = Bt_lo + (mh * 256 + r) * 128 + g * 8;

    bf16x8 bh = *(const bf16x8*)(bh_base);
    bf16x8 bl = *(const bf16x8*)(bl_base);
#pragma unroll
    for (int ch = 0; ch < 4; ++ch) {
        bf16x8 ah = Ahi[ch], al = Alo[ch];
#pragma unroll
        for (int nt = 0; nt < 16; ++nt) {
            bf16x8 bhc = bh, blc = bl;
            int nidx = ch * 16 + nt + 1;
            if (nidx < 64) {
                int nch = nidx >> 4, nnt = nidx & 15;
                bh = *(const bf16x8*)(bh_base + nnt * 2048 + nch * 32);
                bl = *(const bf16x8*)(bl_base + nnt * 2048 + nch * 32);
            }
            acc[nt] = __builtin_amdgcn_mfma_f32_16x16x32_bf16(ah, bhc, acc[nt], 0, 0, 0);
            acc[nt] = __builtin_amdgcn_mfma_f32_16x16x32_bf16(al, bhc, acc[nt], 0, 0, 0);
            acc[nt] = __builtin_amdgcn_mfma_f32_16x16x32_bf16(ah, blc, acc[nt], 0, 0, 0);
        }
    }

    // epilogue: C/D layout col = lane&15, row = g*4 + j (m89-verified)
    // tiles 0-3: Wre, 4-7: Wim, 8-11: Qre, 12-15: Qim ; o = q*16 + r
#pragma unroll
    for (int q = 0; q < 4; ++q) {
        f32x4 wre = acc[q], wim = acc[q + 4];
        f32x4 qre = acc[8 + q], qim = acc[12 + q];
        int o = q * 16 + r;
#pragma unroll
        for (int j = 0; j < 4; ++j) {
            int n = n0 + g * 4 + j;
            Whb[(n * HEADS + mh) * DIM + o] = pack_bf16c(wre[j], wim[j]);
            Qh[(n * HEADS + mh) * DIM + o] = make_float2(qre[j], qim[j]);
        }
    }
}

// ---------------- CSR build ----------------
__global__ void k2a_count(const int* __restrict__ dst, int* __restrict__ counts) {
    int e = blockIdx.x * blockDim.x + threadIdx.x;
    if (e < NE) atomicAdd(&counts[dst[e]], 1);
}

__global__ __launch_bounds__(1024) void k2b_scan(const int* __restrict__ counts,
                                                 int* __restrict__ row_ptr, int* __restrict__ cursor) {
    __shared__ int buf[1024];
    int t = threadIdx.x;
    const int CH = (NN + 1023) / 1024;  // 49
    int i0 = t * CH;
    int i1 = min(i0 + CH, NN);
    int sum = 0;
    for (int i = i0; i < i1; ++i) sum += counts[i];
    buf[t] = sum;
    __syncthreads();
    for (int off = 1; off < 1024; off <<= 1) {
        int x = 0;
        if (t >= off) x = buf[t - off];
        __syncthreads();
        buf[t] += x;
        __syncthreads();
    }
    int run = buf[t] - sum;   // exclusive prefix of this chunk
    for (int i = i0; i < i1; ++i) { row_ptr[i] = run; cursor[i] = run; run += counts[i]; }
    if (t == 1023) row_ptr[NN] = buf[1023];
}

__global__ void k2c_fill(const int* __restrict__ src, const int* __restrict__ dst,
                         int* __restrict__ cursor, int* __restrict__ sorted_src) {
    int e = blockIdx.x * blockDim.x + threadIdx.x;
    if (e < NE) {
        int pos = atomicAdd(&cursor[dst[e]], 1);
        sorted_src[pos] = src[e];
    }
}

// ---------------- K_main: wave per node, 16-lane group per head, 4 dims/lane ----------------
__global__ __launch_bounds__(256) void k_main(
    const float* __restrict__ h_re, const float* __restrict__ h_im,
    const uint4* __restrict__ Whb, float2* __restrict__ Qh_S /* read Qh, write S in place */,
    const int* __restrict__ row_ptr, const int* __restrict__ sorted_src,
    float2* __restrict__ T_out) {
    int wave = threadIdx.x >> 6;
    int lane = threadIdx.x & 63;
    int g = lane >> 4;          // head
    int l = lane & 15;          // dim block
    int n = blockIdx.x * 4 + wave;
    if (n >= NN) return;
    int d0 = l * 4;
    float hre[4], him[4], qre[4], qim[4];
    {
        float4 a = *(const float4*)(h_re + n * DIM + d0);
        float4 b = *(const float4*)(h_im + n * DIM + d0);
        hre[0] = a.x; hre[1] = a.y; hre[2] = a.z; hre[3] = a.w;
        him[0] = b.x; him[1] = b.y; him[2] = b.z; him[3] = b.w;
        const float* qp = (const float*)(Qh_S + (n * HEADS + g) * DIM + d0);
        float4 qa = *(const float4*)qp;
        float4 qb = *(const float4*)(qp + 4);
        qre[0] = qa.x; qim[0] = qa.y; qre[1] = qa.z; qim[1] = qa.w;
        qre[2] = qb.x; qim[2] = qb.y; qre[3] = qb.z; qim[3] = qb.w;
    }
    // t[n][m] = conj(Qh).h  and norm2 = |h|^2, reduced over the 16-lane group
    float tr = 0.f, ti = 0.f, nr = 0.f;
#pragma unroll
    for (int j = 0; j < 4; ++j) {
        tr += qre[j] * hre[j] + qim[j] * him[j];
        ti += qre[j] * him[j] - qim[j] * hre[j];
        nr += hre[j] * hre[j] + him[j] * him[j];
    }
#pragma unroll
    for (int off = 1; off < 16; off <<= 1) {
        tr += __shfl_xor(tr, off, 64);
        ti += __shfl_xor(ti, off, 64);
        nr += __shfl_xor(nr, off, 64);
    }
    float2 tnm = make_float2(tr, ti);
    float inv_n2 = 1.0f / fmaxf(nr, 1e-6f);

    int beg = row_ptr[n], end = row_ptr[n + 1];
    float m_run = -1e30f, l_run = 0.f;
    float Sr[4] = {0, 0, 0, 0}, Si[4] = {0, 0, 0, 0};
    float Tr = 0.f, Ti = 0.f;
    float4 pre = make_float4(0, 0, 0, 0), pim = make_float4(0, 0, 0, 0);
    uint4 pwh = make_uint4(0, 0, 0, 0);
    if (beg < end) {
        int s = sorted_src[beg];
        pre = *(const float4*)(h_re + s * DIM + d0);
        pim = *(const float4*)(h_im + s * DIM + d0);
        pwh = Whb[(s * HEADS + g) * 16 + l];
    }
    for (int pos = beg; pos < end; ++pos) {
        float csr[4] = {pre.x, pre.y, pre.z, pre.w};
        float csi[4] = {pim.x, pim.y, pim.z, pim.w};
        uint4 cw = pwh;
        if (pos + 1 < end) {
            int s2 = sorted_src[pos + 1];
            pre = *(const float4*)(h_re + s2 * DIM + d0);
            pim = *(const float4*)(h_im + s2 * DIM + d0);
            pwh = Whb[(s2 * HEADS + g) * 16 + l];
        }
        float wr[4], wi[4];
        wr[0] = bf_lo(cw.x); wi[0] = bf_hi(cw.x);
        wr[1] = bf_lo(cw.y); wi[1] = bf_hi(cw.y);
        wr[2] = bf_lo(cw.z); wi[2] = bf_hi(cw.z);
        wr[3] = bf_lo(cw.w); wi[3] = bf_hi(cw.w);
        float r0 = 0, r1 = 0, r2 = 0, r3 = 0, r4 = 0;
#pragma unroll
        for (int j = 0; j < 4; ++j) {
            r0 += hre[j] * wr[j] + him[j] * wi[j];     // conj(hd).Wh re
            r1 += hre[j] * wi[j] - him[j] * wr[j];     // conj(hd).Wh im
            r2 += qre[j] * wr[j] + qim[j] * wi[j];     // conj(Qh).Wh re
            r3 += qre[j] * wi[j] - qim[j] * wr[j];     // conj(Qh).Wh im
            r4 += hre[j] * csr[j];                     // h_re[dst].h_re[src]
        }
#pragma unroll
        for (int off = 1; off < 16; off <<= 1) {
            r0 += __shfl_xor(r0, off, 64);
            r1 += __shfl_xor(r1, off, 64);
            r2 += __shfl_xor(r2, off, 64);
            r3 += __shfl_xor(r3, off, 64);
            r4 += __shfl_xor(r4, off, 64);
        }
        float sg = (r4 > 0.f) ? 1.f : ((r4 < 0.f) ? 0.f : 0.5f);
        float cre = SIC * r0 * inv_n2;
        float cim = SIC * r1 * inv_n2;
        float sre = r2 - (cre * tnm.x - cim * tnm.y);
        float sim_ = r3 - (cre * tnm.y + cim * tnm.x);
        float logit = sqrtf(sre * sre + sim_ * sim_) * 0.125f;  // GAMMA/sqrt(D)
        float mnew = fmaxf(m_run, logit);
        float f = __expf(m_run - mnew);    // first edge: exp(-1e30) = 0
        float ex = __expf(logit - mnew);
        float w = ex * sg;
        l_run = l_run * f + ex;
#pragma unroll
        for (int j = 0; j < 4; ++j) {
            Sr[j] = Sr[j] * f + w * csr[j];
            Si[j] = Si[j] * f + w * csi[j];
        }
        Tr = Tr * f + w * cre;
        Ti = Ti * f + w * cim;
        m_run = mnew;
    }
    float inv = 1.0f / (l_run + 1e-16f);
    float* op = (float*)(Qh_S + (n * HEADS + g) * DIM + d0);
    *(float4*)op       = make_float4(Sr[0] * inv, Si[0] * inv, Sr[1] * inv, Si[1] * inv);
    *(float4*)(op + 4) = make_float4(Sr[2] * inv, Si[2] * inv, Sr[3] * inv, Si[3] * inv);
    if (l == 0) T_out[n * HEADS + g] = make_float2(Tr * inv, Ti * inv);
}

// ---------------- K5: MFMA GEMM U = S @ B2 ; fused NodeNorm + ModReLU epilogue ------
// A[n][k] = ((float*)S)[n*512 + k]  (k = m*128 + i*2 + comp), hi/lo bf16 split.
// C[n][c_out], c_out = comp_out*64 + o : comp_out=0 -> U_re, 1 -> U_im.
__global__ __launch_bounds__(256) void k5_mfma(
    const float* __restrict__ h_re, const float* __restrict__ h_im,
    const float* __restrict__ S_in,  // [NN][512] floats (the Qh/S buffer)
    const float2* __restrict__ T_in,
    const __bf16* __restrict__ Bt_hi, const __bf16* __restrict__ Bt_lo,  // [128][512]
    const float* __restrict__ gate_raw, const float* __restrict__ modrelu_b,
    float2* __restrict__ out) {
    int w = threadIdx.x >> 6, l = threadIdx.x & 63;
    int n0 = blockIdx.x * 64 + w * 16;
    if (n0 >= NN) return;                    // tail block: only wave 0 (rows 49984..49999)
    int r = l & 15, g = l >> 4;
    int nodeA = min(n0 + r, NN - 1);

    f32x4 acc[8];
#pragma unroll
    for (int t = 0; t < 8; ++t) acc[t] = {0.f, 0.f, 0.f, 0.f};

    const float* arow = S_in + (size_t)nodeA * 512;
#pragma unroll
    for (int ch = 0; ch < 16; ++ch) {
        const float* p = arow + ch * 32 + g * 8;
        float4 a = *(const float4*)p;
        float4 b = *(const float4*)(p + 4);
        float v[8] = {a.x, a.y, a.z, a.w, b.x, b.y, b.z, b.w};
        bf16x8 ah, al;
#pragma unroll
        for (int j = 0; j < 8; ++j) {
            __bf16 hi = (__bf16)v[j];
            ah[j] = hi;
            al[j] = (__bf16)(v[j] - (float)hi);
        }
        const __bf16* bh_base = Bt_hi + r * 512 + ch * 32 + g * 8;
        const __bf16* bl_base = Bt_lo + r * 512 + ch * 32 + g * 8;
#pragma unroll
        for (int nt = 0; nt < 8; ++nt) {
            bf16x8 bh = *(const bf16x8*)(bh_base + nt * 16 * 512);
            bf16x8 bl = *(const bf16x8*)(bl_base + nt * 16 * 512);
            acc[nt] = __builtin_amdgcn_mfma_f32_16x16x32_bf16(ah, bh, acc[nt], 0, 0, 0);
            acc[nt] = __builtin_amdgcn_mfma_f32_16x16x32_bf16(al, bh, acc[nt], 0, 0, 0);
            acc[nt] = __builtin_amdgcn_mfma_f32_16x16x32_bf16(ah, bl, acc[nt], 0, 0, 0);
        }
    }

    // epilogue: lane holds rows n0 + g*4 + j (j=0..3), cols o = q*16 + r (q=0..3):
    //   U_re = acc[q][j], U_im = acc[q+4][j]
    float gate = 1.0f / (1.0f + expf(-gate_raw[0]));
    float bo[4];
#pragma unroll
    for (int q = 0; q < 4; ++q) bo[q] = modrelu_b[q * 16 + r];

#pragma unroll
    for (int j = 0; j < 4; ++j) {
        int n = n0 + g * 4 + j;
        int nc = min(n, NN - 1);
        float2 Ts = make_float2(0.f, 0.f);
#pragma unroll
        for (int m = 0; m < HEADS; ++m) {
            float2 tv = T_in[nc * HEADS + m];
            Ts.x += tv.x; Ts.y += tv.y;
        }
        float xr_[4], xi_[4];
        float sr = 0.f, si = 0.f, qr = 0.f, qi = 0.f;
#pragma unroll
        for (int q = 0; q < 4; ++q) {
            int o = q * 16 + r;
            float hr = h_re[nc * DIM + o];
            float hi = h_im[nc * DIM + o];
            float nre = hr + acc[q][j]     - gate * (Ts.x * hr - Ts.y * hi);
            float nim = hi + acc[q + 4][j] - gate * (Ts.x * hi + Ts.y * hr);
            xr_[q] = nre; xi_[q] = nim;
            sr += nre; si += nim; qr += nre * nre; qi += nim * nim;
        }
#pragma unroll
        for (int off = 1; off < 16; off <<= 1) {
            sr += __shfl_xor(sr, off, 64);
            si += __shfl_xor(si, off, 64);
            qr += __shfl_xor(qr, off, 64);
            qi += __shfl_xor(qi, off, 64);
        }
        float mean_r = sr * (1.f / DIM), mean_i = si * (1.f / DIM);
        float var_r = (qr - DIM * mean_r * mean_r) * (1.f / (DIM - 1));
        float var_i = (qi - DIM * mean_i * mean_i) * (1.f / (DIM - 1));
        float std_r = fmaxf(sqrtf(fmaxf(var_r, 0.f)), 1e-5f);
        float std_i = fmaxf(sqrtf(fmaxf(var_i, 0.f)), 1e-5f);
        if (n < NN) {
#pragma unroll
            for (int q = 0; q < 4; ++q) {
                float xr = (xr_[q] - mean_r) / std_r;
                float xi = (xi_[q] - mean_i) / std_i;
                float mag = fmaxf(sqrtf(xr * xr + xi * xi), 1e-6f);
                float gg = fmaxf(mag + bo[q], 0.f);
                float sc = gg / mag;
                out[n * DIM + q * 16 + r] = make_float2(xr * sc, xi * sc);
            }
        }
    }
}

extern "C" void kernel_launch(void* const* d_in, const int* in_sizes, int n_in,
                              void* d_out, int out_size, void* d_ws, size_t ws_size,
                              hipStream_t stream) {
    const float* h_re = (const float*)d_in[0];
    const float* h_im = (const float*)d_in[1];
    const float* W_re = (const float*)d_in[2];
    const float* W_im = (const float*)d_in[3];
    const float* Q_re = (const float*)d_in[4];
    const float* Q_im = (const float*)d_in[5];
    const float* gate_raw = (const float*)d_in[6];
    const float* b = (const float*)d_in[7];
    const int* src = (const int*)d_in[8];
    const int* dst = (const int*)d_in[9];

    char* ws = (char*)d_ws;
    size_t off = 0;
    auto alloc = [&](size_t bytes) {
        void* p = ws + off;
        off = (off + bytes + 255) & ~(size_t)255;
        return p;
    };
    __bf16* Bt_hi = (__bf16*)alloc((size_t)1024 * 128 * sizeof(__bf16));
    __bf16* Bt_lo = (__bf16*)alloc((size_t)1024 * 128 * sizeof(__bf16));
    __bf16* B2_hi = (__bf16*)alloc((size_t)128 * 512 * sizeof(__bf16));
    __bf16* B2_lo = (__bf16*)alloc((size_t)128 * 512 * sizeof(__bf16));
    unsigned* Whb = (unsigned*)alloc((size_t)NN * HEADS * DIM * sizeof(unsigned));
    float2* Qh = (float2*)alloc((size_t)NN * HEADS * DIM * sizeof(float2));  // reused as S
    float2* T_buf = (float2*)alloc((size_t)NN * HEADS * sizeof(float2));
    int* counts = (int*)alloc((size_t)NN * sizeof(int));
    int* row_ptr = (int*)alloc((size_t)(NN + 1) * sizeof(int));
    int* cursor = (int*)alloc((size_t)NN * sizeof(int));
    int* sorted_src = (int*)alloc((size_t)NE * sizeof(int));

    hipMemsetAsync(counts, 0, (size_t)NN * sizeof(int), stream);
    k0b_build<<<(1024 * 128 + 255) / 256, 256, 0, stream>>>(W_re, W_im, Q_re, Q_im, Bt_hi, Bt_lo);
    k0c_build<<<(128 * 512 + 255) / 256, 256, 0, stream>>>(W_re, W_im, B2_hi, B2_lo);
    k1_mfma<<<4 * ((NN + 63) / 64), 256, 0, stream>>>(h_re, h_im, Bt_hi, Bt_lo, Whb, Qh);
    k2a_count<<<(NE + 255) / 256, 256, 0, stream>>>(dst, counts);
    k2b_scan<<<1, 1024, 0, stream>>>(counts, row_ptr, cursor);
    k2c_fill<<<(NE + 255) / 256, 256, 0, stream>>>(src, dst, cursor, sorted_src);
    k_main<<<(NN + 3) / 4, 256, 0, stream>>>(h_re, h_im, (const uint4*)Whb, Qh, row_ptr, sorted_src, T_buf);
    k5_mfma<<<(NN + 63) / 64, 256, 0, stream>>>(h_re, h_im, (const float*)Qh, T_buf, B2_hi, B2_lo, gate_raw, b, (float2*)d_out);
}

// Round 5
// 596.464 us; speedup vs baseline: 1.9441x; 1.0930x over previous
//
#include <hip/hip_runtime.h>
#include <hip/hip_bf16.h>
#include <math.h>

#define NN 50000
#define NE 400000
#define DIM 64
#define HEADS 4
#define SIC 0.5f

typedef __bf16 bf16x8 __attribute__((ext_vector_type(8)));
typedef float f32x4 __attribute__((ext_vector_type(4)));

__device__ __forceinline__ float bf_lo(unsigned u) { return __uint_as_float(u << 16); }
__device__ __forceinline__ float bf_hi(unsigned u) { return __uint_as_float(u & 0xffff0000u); }

__device__ __forceinline__ unsigned pack_bf16c(float re, float im) {
    __bf16 r = (__bf16)re, i = (__bf16)im;
    unsigned short lo = __builtin_bit_cast(unsigned short, r);
    unsigned short hi = __builtin_bit_cast(unsigned short, i);
    return (unsigned)lo | ((unsigned)hi << 16);
}

// ---------------- K0b: weight table for k1 GEMM: Bt[c][k], [1024][128] bf16 hi/lo ------
// c = mh*256 + mat*128 + comp*64 + o ; k<64 -> real input i=k, k>=64 -> imag i=k-64
__global__ void k0b_build(const float* __restrict__ Wre, const float* __restrict__ Wim,
                          const float* __restrict__ Qre, const float* __restrict__ Qim,
                          __bf16* __restrict__ Bt_hi, __bf16* __restrict__ Bt_lo) {
    int tid = blockIdx.x * blockDim.x + threadIdx.x;   // c*128 + k
    if (tid >= 1024 * 128) return;
    int c = tid >> 7, k = tid & 127;
    int mh = c >> 8, cm = c & 255;
    int mat = cm >> 7, comp = (cm >> 6) & 1, o = cm & 63;
    int part = k >> 6, i = k & 63;
    const float* Mre = mat ? Qre : Wre;
    const float* Mim = mat ? Qim : Wim;
    int widx = (mh * DIM + o) * DIM + i;
    float v;
    if (comp == 0) v = part ? -Mim[widx] : Mre[widx];
    else           v = part ?  Mre[widx] : Mim[widx];
    __bf16 hi = (__bf16)v;
    Bt_hi[tid] = hi;
    Bt_lo[tid] = (__bf16)(v - (float)hi);
}

// ---------------- K0c: weight table for k5 GEMM: B2t[c_out][k], [128][512] bf16 hi/lo --
// k = m*128 + i*2 + cin (cin: 0=re,1=im of S); c_out = comp_out*64 + o
__global__ void k0c_build(const float* __restrict__ Wre, const float* __restrict__ Wim,
                          __bf16* __restrict__ Bt_hi, __bf16* __restrict__ Bt_lo) {
    int tid = blockIdx.x * blockDim.x + threadIdx.x;   // c_out*512 + k
    if (tid >= 128 * 512) return;
    int c_out = tid >> 9, k = tid & 511;
    int comp_out = c_out >> 6, o = c_out & 63;
    int m = k >> 7, cin = k & 1, i = (k >> 1) & 63;
    int widx = (m * DIM + o) * DIM + i;
    float v;
    if (cin == 0) v = comp_out ? Wim[widx] : Wre[widx];
    else          v = comp_out ? Wre[widx] : -Wim[widx];
    __bf16 hi = (__bf16)v;
    Bt_hi[tid] = hi;
    Bt_lo[tid] = (__bf16)(v - (float)hi);
}

// ---------------- kA: pre-convert node features to bf16 hi/lo [NN][128] ----------------
// A[n][k] = k<64 ? h_re[n][k] : h_im[n][k-64]
__global__ void kA_conv(const float* __restrict__ h_re, const float* __restrict__ h_im,
                        __bf16* __restrict__ Ahi, __bf16* __restrict__ Alo) {
    int tid = blockIdx.x * blockDim.x + threadIdx.x;
    if (tid >= NN * 128) return;
    int n = tid >> 7, k = tid & 127;
    float v = (k < 64) ? h_re[n * 64 + k] : h_im[n * 64 + (k - 64)];
    __bf16 hi = (__bf16)v;
    Ahi[tid] = hi;
    Alo[tid] = (__bf16)(v - (float)hi);
}

// ---------------- K1_ws: weights-stationary MFMA GEMM -----------------------------------
// Wave = (mh, mat, o-block): holds weight frags (2 comp-tiles x 4 k-chunks, hi/lo) in regs,
// streams 16-node tiles with 1-tile double buffer. Output packed bf16 (Whb / Qhb).
__global__ __launch_bounds__(256) void k1_ws(
    const __bf16* __restrict__ Ahi, const __bf16* __restrict__ Alo,     // [NN][128]
    const __bf16* __restrict__ Bt_hi, const __bf16* __restrict__ Bt_lo, // [1024][128]
    unsigned* __restrict__ Whb, unsigned* __restrict__ Qhb) {
    int w = threadIdx.x >> 6, l = threadIdx.x & 63;
    int r = l & 15, g = l >> 4;
    int cls = blockIdx.x & 7;
    int chunk = blockIdx.x >> 3;
    int mh = cls >> 1, mat = cls & 1;
    int c0 = mh * 256 + mat * 128 + w * 16;
    int nbase = chunk * 256;
    unsigned* Out = mat ? Qhb : Whb;

    bf16x8 Wh_[2][4], Wl_[2][4];
#pragma unroll
    for (int t = 0; t < 2; ++t)
#pragma unroll
        for (int ch = 0; ch < 4; ++ch) {
            int boff = (c0 + t * 64 + r) * 128 + ch * 32 + g * 8;
            Wh_[t][ch] = *(const bf16x8*)(Bt_hi + boff);
            Wl_[t][ch] = *(const bf16x8*)(Bt_lo + boff);
        }

    bf16x8 N0h[4], N0l[4], N1h[4], N1l[4];
    {
        int nc = min(nbase + r, NN - 1);
#pragma unroll
        for (int ch = 0; ch < 4; ++ch) {
            int aoff = nc * 128 + ch * 32 + g * 8;
            N0h[ch] = *(const bf16x8*)(Ahi + aoff);
            N0l[ch] = *(const bf16x8*)(Alo + aoff);
        }
    }

#pragma unroll
    for (int nt = 0; nt < 16; ++nt) {
        const bf16x8 (&Nh)[4] = (nt & 1) ? N1h : N0h;
        const bf16x8 (&Nl)[4] = (nt & 1) ? N1l : N0l;
        bf16x8 (&Ph)[4] = (nt & 1) ? N0h : N1h;
        bf16x8 (&Pl)[4] = (nt & 1) ? N0l : N1l;
        if (nt + 1 < 16) {
            int nc = min(nbase + (nt + 1) * 16 + r, NN - 1);
#pragma unroll
            for (int ch = 0; ch < 4; ++ch) {
                int aoff = nc * 128 + ch * 32 + g * 8;
                Ph[ch] = *(const bf16x8*)(Ahi + aoff);
                Pl[ch] = *(const bf16x8*)(Alo + aoff);
            }
        }
        f32x4 a0 = {0.f, 0.f, 0.f, 0.f}, a1 = {0.f, 0.f, 0.f, 0.f};
#pragma unroll
        for (int ch = 0; ch < 4; ++ch) {
            a0 = __builtin_amdgcn_mfma_f32_16x16x32_bf16(Wh_[0][ch], Nh[ch], a0, 0, 0, 0);
            a1 = __builtin_amdgcn_mfma_f32_16x16x32_bf16(Wh_[1][ch], Nh[ch], a1, 0, 0, 0);
            a0 = __builtin_amdgcn_mfma_f32_16x16x32_bf16(Wl_[0][ch], Nh[ch], a0, 0, 0, 0);
            a1 = __builtin_amdgcn_mfma_f32_16x16x32_bf16(Wl_[1][ch], Nh[ch], a1, 0, 0, 0);
            a0 = __builtin_amdgcn_mfma_f32_16x16x32_bf16(Wh_[0][ch], Nl[ch], a0, 0, 0, 0);
            a1 = __builtin_amdgcn_mfma_f32_16x16x32_bf16(Wh_[1][ch], Nl[ch], a1, 0, 0, 0);
        }
        // D[c][n]: col = lane&15 = node offset, row = g*4+j = c offset (m89 layout)
        int n = nbase + nt * 16 + r;
        if (n < NN) {
            uint4 u;
            u.x = pack_bf16c(a0[0], a1[0]);
            u.y = pack_bf16c(a0[1], a1[1]);
            u.z = pack_bf16c(a0[2], a1[2]);
            u.w = pack_bf16c(a0[3], a1[3]);
            *(uint4*)&Out[(n * HEADS + mh) * DIM + (c0 & 63) + g * 4] = u;
        }
    }
}

// ---------------- CSR build ----------------
__global__ void k2a_count(const int* __restrict__ dst, int* __restrict__ counts) {
    int e = blockIdx.x * blockDim.x + threadIdx.x;
    if (e < NE) atomicAdd(&counts[dst[e]], 1);
}

__global__ __launch_bounds__(1024) void k2b_scan(const int* __restrict__ counts,
                                                 int* __restrict__ row_ptr, int* __restrict__ cursor) {
    __shared__ int buf[1024];
    int t = threadIdx.x;
    const int CH = (NN + 1023) / 1024;  // 49
    int i0 = t * CH;
    int i1 = min(i0 + CH, NN);
    int sum = 0;
    for (int i = i0; i < i1; ++i) sum += counts[i];
    buf[t] = sum;
    __syncthreads();
    for (int off = 1; off < 1024; off <<= 1) {
        int x = 0;
        if (t >= off) x = buf[t - off];
        __syncthreads();
        buf[t] += x;
        __syncthreads();
    }
    int run = buf[t] - sum;
    for (int i = i0; i < i1; ++i) { row_ptr[i] = run; cursor[i] = run; run += counts[i]; }
    if (t == 1023) row_ptr[NN] = buf[1023];
}

__global__ void k2c_fill(const int* __restrict__ src, const int* __restrict__ dst,
                         int* __restrict__ cursor, int* __restrict__ sorted_src) {
    int e = blockIdx.x * blockDim.x + threadIdx.x;
    if (e < NE) {
        int pos = atomicAdd(&cursor[dst[e]], 1);
        sorted_src[pos] = src[e];
    }
}

// ---------------- K_main: wave per node, 16-lane group per head, 2-edge pipeline ------
__global__ __launch_bounds__(256) void k_main(
    const float* __restrict__ h_re, const float* __restrict__ h_im,
    const uint4* __restrict__ Whb, const uint4* __restrict__ Qhb,
    const int* __restrict__ row_ptr, const int* __restrict__ sorted_src,
    __bf16* __restrict__ Sb, float2* __restrict__ T_out) {
    int wave = threadIdx.x >> 6;
    int lane = threadIdx.x & 63;
    int g = lane >> 4;          // head
    int l = lane & 15;          // dim block
    int n = blockIdx.x * 4 + wave;
    if (n >= NN) return;
    int d0 = l * 4;
    float hre[4], him[4], qre[4], qim[4];
    {
        float4 a = *(const float4*)(h_re + n * DIM + d0);
        float4 b = *(const float4*)(h_im + n * DIM + d0);
        hre[0] = a.x; hre[1] = a.y; hre[2] = a.z; hre[3] = a.w;
        him[0] = b.x; him[1] = b.y; him[2] = b.z; him[3] = b.w;
        uint4 qw = Qhb[(n * HEADS + g) * 16 + l];
        qre[0] = bf_lo(qw.x); qim[0] = bf_hi(qw.x);
        qre[1] = bf_lo(qw.y); qim[1] = bf_hi(qw.y);
        qre[2] = bf_lo(qw.z); qim[2] = bf_hi(qw.z);
        qre[3] = bf_lo(qw.w); qim[3] = bf_hi(qw.w);
    }
    // t[n][m] = conj(Qh).h ; norm2 = |h|^2  (16-lane group reduce)
    float tr = 0.f, ti = 0.f, nr = 0.f;
#pragma unroll
    for (int j = 0; j < 4; ++j) {
        tr += qre[j] * hre[j] + qim[j] * him[j];
        ti += qre[j] * him[j] - qim[j] * hre[j];
        nr += hre[j] * hre[j] + him[j] * him[j];
    }
#pragma unroll
    for (int off = 1; off < 16; off <<= 1) {
        tr += __shfl_xor(tr, off, 64);
        ti += __shfl_xor(ti, off, 64);
        nr += __shfl_xor(nr, off, 64);
    }
    float2 tnm = make_float2(tr, ti);
    float inv_n2 = 1.0f / fmaxf(nr, 1e-6f);

    int beg = row_ptr[n], end = row_ptr[n + 1];
    float m_run = -1e30f, l_run = 0.f;
    float Sr[4] = {0, 0, 0, 0}, Si[4] = {0, 0, 0, 0};
    float Tr = 0.f, Ti = 0.f;

    auto ld = [&](int p, float4& rr, float4& ii, uint4& ww) {
        int s = sorted_src[p];
        rr = *(const float4*)(h_re + s * DIM + d0);
        ii = *(const float4*)(h_im + s * DIM + d0);
        ww = Whb[(s * HEADS + g) * 16 + l];
    };
    auto process = [&](const float4& cr4, const float4& ci4, const uint4& cw) {
        float csr[4] = {cr4.x, cr4.y, cr4.z, cr4.w};
        float csi[4] = {ci4.x, ci4.y, ci4.z, ci4.w};
        float wr[4], wi[4];
        wr[0] = bf_lo(cw.x); wi[0] = bf_hi(cw.x);
        wr[1] = bf_lo(cw.y); wi[1] = bf_hi(cw.y);
        wr[2] = bf_lo(cw.z); wi[2] = bf_hi(cw.z);
        wr[3] = bf_lo(cw.w); wi[3] = bf_hi(cw.w);
        float r0 = 0, r1 = 0, r2 = 0, r3 = 0, r4 = 0;
#pragma unroll
        for (int j = 0; j < 4; ++j) {
            r0 += hre[j] * wr[j] + him[j] * wi[j];
            r1 += hre[j] * wi[j] - him[j] * wr[j];
            r2 += qre[j] * wr[j] + qim[j] * wi[j];
            r3 += qre[j] * wi[j] - qim[j] * wr[j];
            r4 += hre[j] * csr[j];
        }
#pragma unroll
        for (int off = 1; off < 16; off <<= 1) {
            r0 += __shfl_xor(r0, off, 64);
            r1 += __shfl_xor(r1, off, 64);
            r2 += __shfl_xor(r2, off, 64);
            r3 += __shfl_xor(r3, off, 64);
            r4 += __shfl_xor(r4, off, 64);
        }
        float sg = (r4 > 0.f) ? 1.f : ((r4 < 0.f) ? 0.f : 0.5f);
        float cre = SIC * r0 * inv_n2;
        float cim = SIC * r1 * inv_n2;
        float sre = r2 - (cre * tnm.x - cim * tnm.y);
        float sim_ = r3 - (cre * tnm.y + cim * tnm.x);
        float logit = sqrtf(sre * sre + sim_ * sim_) * 0.125f;
        float mnew = fmaxf(m_run, logit);
        float f = __expf(m_run - mnew);
        float ex = __expf(logit - mnew);
        float wgt = ex * sg;
        l_run = l_run * f + ex;
#pragma unroll
        for (int j = 0; j < 4; ++j) {
            Sr[j] = Sr[j] * f + wgt * csr[j];
            Si[j] = Si[j] * f + wgt * csi[j];
        }
        Tr = Tr * f + wgt * cre;
        Ti = Ti * f + wgt * cim;
        m_run = mnew;
    };

    float4 Ar = make_float4(0, 0, 0, 0), Ai = Ar, Br = Ar, Bi = Ar;
    uint4 Aw = make_uint4(0, 0, 0, 0), Bw = Aw;
    if (beg < end) ld(beg, Ar, Ai, Aw);
    if (beg + 1 < end) ld(beg + 1, Br, Bi, Bw);
    for (int pos = beg; pos < end; pos += 2) {
        float4 ar = Ar, ai = Ai; uint4 aw = Aw;
        float4 br = Br, bi = Bi; uint4 bw = Bw;
        bool hasB = (pos + 1 < end);
        if (pos + 2 < end) ld(pos + 2, Ar, Ai, Aw);
        if (pos + 3 < end) ld(pos + 3, Br, Bi, Bw);
        process(ar, ai, aw);
        if (hasB) process(br, bi, bw);
    }

    float inv = 1.0f / (l_run + 1e-16f);
    bf16x8 sb;
#pragma unroll
    for (int j = 0; j < 4; ++j) {
        sb[2 * j]     = (__bf16)(Sr[j] * inv);
        sb[2 * j + 1] = (__bf16)(Si[j] * inv);
    }
    *(bf16x8*)(Sb + n * 512 + g * 128 + d0 * 2) = sb;
    if (l == 0) T_out[n * HEADS + g] = make_float2(Tr * inv, Ti * inv);
}

// ---------------- K5_ws: nodes-stationary MFMA GEMM + fused NodeNorm/ModReLU ----------
// A = Sb (bf16 single) [16 nodes/wave][512k] stationary; B = weights streamed hi/lo
// through an 8-slot static pipeline. acc[8] covers the full 128-col row per wave.
__global__ __launch_bounds__(256) void k5_ws(
    const float* __restrict__ h_re, const float* __restrict__ h_im,
    const __bf16* __restrict__ Sb,   // [NN][512]
    const float2* __restrict__ T_in,
    const __bf16* __restrict__ B2_hi, const __bf16* __restrict__ B2_lo,  // [128][512]
    const float* __restrict__ gate_raw, const float* __restrict__ modrelu_b,
    float2* __restrict__ out) {
    int w = threadIdx.x >> 6, l = threadIdx.x & 63;
    int n0 = blockIdx.x * 64 + w * 16;
    if (n0 >= NN) return;
    int r = l & 15, g = l >> 4;
    int nodeA = min(n0 + r, NN - 1);

    bf16x8 A_[16];
#pragma unroll
    for (int ch = 0; ch < 16; ++ch)
        A_[ch] = *(const bf16x8*)(Sb + nodeA * 512 + ch * 32 + g * 8);

    bf16x8 Bh[8], Bl[8];
#pragma unroll
    for (int s = 0; s < 8; ++s) {
        int boff = r * 512 + s * 32 + g * 8;   // flat frag s -> (nt=0, ch=s)
        Bh[s] = *(const bf16x8*)(B2_hi + boff);
        Bl[s] = *(const bf16x8*)(B2_lo + boff);
    }

    f32x4 acc[8];
#pragma unroll
    for (int t = 0; t < 8; ++t) acc[t] = {0.f, 0.f, 0.f, 0.f};

#pragma unroll
    for (int nt = 0; nt < 8; ++nt) {
#pragma unroll
        for (int ch = 0; ch < 16; ++ch) {
            const int slot = ch & 7;
            bf16x8 bh = Bh[slot], bl = Bl[slot];
            int fl = nt * 16 + ch + 8;           // prefetch 8 frags ahead
            if (fl < 128) {
                int fnt = fl >> 4, fch = fl & 15;
                int boff = (fnt * 16 + r) * 512 + fch * 32 + g * 8;
                Bh[slot] = *(const bf16x8*)(B2_hi + boff);
                Bl[slot] = *(const bf16x8*)(B2_lo + boff);
            }
            acc[nt] = __builtin_amdgcn_mfma_f32_16x16x32_bf16(A_[ch], bh, acc[nt], 0, 0, 0);
            acc[nt] = __builtin_amdgcn_mfma_f32_16x16x32_bf16(A_[ch], bl, acc[nt], 0, 0, 0);
        }
    }

    // epilogue: rows n = n0 + g*4 + j ; cols o = q*16 + r ; re = acc[q], im = acc[q+4]
    float gate = 1.0f / (1.0f + expf(-gate_raw[0]));
    float bo[4];
#pragma unroll
    for (int q = 0; q < 4; ++q) bo[q] = modrelu_b[q * 16 + r];

#pragma unroll
    for (int j = 0; j < 4; ++j) {
        int n = n0 + g * 4 + j;
        int nc = min(n, NN - 1);
        float2 Ts = make_float2(0.f, 0.f);
#pragma unroll
        for (int m = 0; m < HEADS; ++m) {
            float2 tv = T_in[nc * HEADS + m];
            Ts.x += tv.x; Ts.y += tv.y;
        }
        float xr_[4], xi_[4];
        float sr = 0.f, si = 0.f, qr = 0.f, qi = 0.f;
#pragma unroll
        for (int q = 0; q < 4; ++q) {
            int o = q * 16 + r;
            float hr = h_re[nc * DIM + o];
            float hi = h_im[nc * DIM + o];
            float nre = hr + acc[q][j]     - gate * (Ts.x * hr - Ts.y * hi);
            float nim = hi + acc[q + 4][j] - gate * (Ts.x * hi + Ts.y * hr);
            xr_[q] = nre; xi_[q] = nim;
            sr += nre; si += nim; qr += nre * nre; qi += nim * nim;
        }
#pragma unroll
        for (int off = 1; off < 16; off <<= 1) {
            sr += __shfl_xor(sr, off, 64);
            si += __shfl_xor(si, off, 64);
            qr += __shfl_xor(qr, off, 64);
            qi += __shfl_xor(qi, off, 64);
        }
        float mean_r = sr * (1.f / DIM), mean_i = si * (1.f / DIM);
        float var_r = (qr - DIM * mean_r * mean_r) * (1.f / (DIM - 1));
        float var_i = (qi - DIM * mean_i * mean_i) * (1.f / (DIM - 1));
        float std_r = fmaxf(sqrtf(fmaxf(var_r, 0.f)), 1e-5f);
        float std_i = fmaxf(sqrtf(fmaxf(var_i, 0.f)), 1e-5f);
        if (n < NN) {
#pragma unroll
            for (int q = 0; q < 4; ++q) {
                float xr = (xr_[q] - mean_r) / std_r;
                float xi = (xi_[q] - mean_i) / std_i;
                float mag = fmaxf(sqrtf(xr * xr + xi * xi), 1e-6f);
                float gg = fmaxf(mag + bo[q], 0.f);
                float sc = gg / mag;
                out[n * DIM + q * 16 + r] = make_float2(xr * sc, xi * sc);
            }
        }
    }
}

extern "C" void kernel_launch(void* const* d_in, const int* in_sizes, int n_in,
                              void* d_out, int out_size, void* d_ws, size_t ws_size,
                              hipStream_t stream) {
    const float* h_re = (const float*)d_in[0];
    const float* h_im = (const float*)d_in[1];
    const float* W_re = (const float*)d_in[2];
    const float* W_im = (const float*)d_in[3];
    const float* Q_re = (const float*)d_in[4];
    const float* Q_im = (const float*)d_in[5];
    const float* gate_raw = (const float*)d_in[6];
    const float* b = (const float*)d_in[7];
    const int* src = (const int*)d_in[8];
    const int* dst = (const int*)d_in[9];

    char* ws = (char*)d_ws;
    size_t off = 0;
    auto alloc = [&](size_t bytes) {
        void* p = ws + off;
        off = (off + bytes + 255) & ~(size_t)255;
        return p;
    };
    __bf16* Bt_hi = (__bf16*)alloc((size_t)1024 * 128 * sizeof(__bf16));
    __bf16* Bt_lo = (__bf16*)alloc((size_t)1024 * 128 * sizeof(__bf16));
    __bf16* B2_hi = (__bf16*)alloc((size_t)128 * 512 * sizeof(__bf16));
    __bf16* B2_lo = (__bf16*)alloc((size_t)128 * 512 * sizeof(__bf16));
    __bf16* Ahi = (__bf16*)alloc((size_t)NN * 128 * sizeof(__bf16));
    __bf16* Alo = (__bf16*)alloc((size_t)NN * 128 * sizeof(__bf16));
    unsigned* Whb = (unsigned*)alloc((size_t)NN * HEADS * DIM * sizeof(unsigned));
    unsigned* Qhb = (unsigned*)alloc((size_t)NN * HEADS * DIM * sizeof(unsigned));
    __bf16* Sb = (__bf16*)alloc((size_t)NN * 512 * sizeof(__bf16));
    float2* T_buf = (float2*)alloc((size_t)NN * HEADS * sizeof(float2));
    int* counts = (int*)alloc((size_t)NN * sizeof(int));
    int* row_ptr = (int*)alloc((size_t)(NN + 1) * sizeof(int));
    int* cursor = (int*)alloc((size_t)NN * sizeof(int));
    int* sorted_src = (int*)alloc((size_t)NE * sizeof(int));

    hipMemsetAsync(counts, 0, (size_t)NN * sizeof(int), stream);
    k0b_build<<<(1024 * 128 + 255) / 256, 256, 0, stream>>>(W_re, W_im, Q_re, Q_im, Bt_hi, Bt_lo);
    k0c_build<<<(128 * 512 + 255) / 256, 256, 0, stream>>>(W_re, W_im, B2_hi, B2_lo);
    kA_conv<<<(NN * 128 + 255) / 256, 256, 0, stream>>>(h_re, h_im, Ahi, Alo);
    k1_ws<<<8 * ((NN + 255) / 256), 256, 0, stream>>>(Ahi, Alo, Bt_hi, Bt_lo, Whb, Qhb);
    k2a_count<<<(NE + 255) / 256, 256, 0, stream>>>(dst, counts);
    k2b_scan<<<1, 1024, 0, stream>>>(counts, row_ptr, cursor);
    k2c_fill<<<(NE + 255) / 256, 256, 0, stream>>>(src, dst, cursor, sorted_src);
    k_main<<<(NN + 3) / 4, 256, 0, stream>>>(h_re, h_im, (const uint4*)Whb, (const uint4*)Qhb,
                                             row_ptr, sorted_src, Sb, T_buf);
    k5_ws<<<(NN + 63) / 64, 256, 0, stream>>>(h_re, h_im, Sb, T_buf, B2_hi, B2_lo,
                                              gate_raw, b, (float2*)d_out);
}

// Round 7
// 548.018 us; speedup vs baseline: 2.1160x; 1.0884x over previous
//
#include <hip/hip_runtime.h>
#include <hip/hip_bf16.h>
#include <math.h>

#define NN 50000
#define NE 400000
#define DIM 64
#define HEADS 4
#define SIC 0.5f

typedef __bf16 bf16x8 __attribute__((ext_vector_type(8)));
typedef float f32x4 __attribute__((ext_vector_type(4)));

__device__ __forceinline__ float bf_lo(unsigned u) { return __uint_as_float(u << 16); }
__device__ __forceinline__ float bf_hi(unsigned u) { return __uint_as_float(u & 0xffff0000u); }

__device__ __forceinline__ unsigned pack_bf16c(float re, float im) {
    __bf16 r = (__bf16)re, i = (__bf16)im;
    unsigned short lo = __builtin_bit_cast(unsigned short, r);
    unsigned short hi = __builtin_bit_cast(unsigned short, i);
    return (unsigned)lo | ((unsigned)hi << 16);
}

// ---------------- K0b: weight table for k1 GEMM: Bt[c][k], [1024][128] bf16 hi/lo ------
// c = mh*256 + mat*128 + comp*64 + o ; k<64 -> real input i=k, k>=64 -> imag i=k-64
__global__ void k0b_build(const float* __restrict__ Wre, const float* __restrict__ Wim,
                          const float* __restrict__ Qre, const float* __restrict__ Qim,
                          __bf16* __restrict__ Bt_hi, __bf16* __restrict__ Bt_lo) {
    int tid = blockIdx.x * blockDim.x + threadIdx.x;   // c*128 + k
    if (tid >= 1024 * 128) return;
    int c = tid >> 7, k = tid & 127;
    int mh = c >> 8, cm = c & 255;
    int mat = cm >> 7, comp = (cm >> 6) & 1, o = cm & 63;
    int part = k >> 6, i = k & 63;
    const float* Mre = mat ? Qre : Wre;
    const float* Mim = mat ? Qim : Wim;
    int widx = (mh * DIM + o) * DIM + i;
    float v;
    if (comp == 0) v = part ? -Mim[widx] : Mre[widx];
    else           v = part ?  Mre[widx] : Mim[widx];
    __bf16 hi = (__bf16)v;
    Bt_hi[tid] = hi;
    Bt_lo[tid] = (__bf16)(v - (float)hi);
}

// ---------------- K0c: weight table for k5 GEMM: B2t[c_out][k], [128][512] bf16 hi/lo --
__global__ void k0c_build(const float* __restrict__ Wre, const float* __restrict__ Wim,
                          __bf16* __restrict__ Bt_hi, __bf16* __restrict__ Bt_lo) {
    int tid = blockIdx.x * blockDim.x + threadIdx.x;   // c_out*512 + k
    if (tid >= 128 * 512) return;
    int c_out = tid >> 9, k = tid & 511;
    int comp_out = c_out >> 6, o = c_out & 63;
    int m = k >> 7, cin = k & 1, i = (k >> 1) & 63;
    int widx = (m * DIM + o) * DIM + i;
    float v;
    if (cin == 0) v = comp_out ? Wim[widx] : Wre[widx];
    else          v = comp_out ? Wre[widx] : -Wim[widx];
    __bf16 hi = (__bf16)v;
    Bt_hi[tid] = hi;
    Bt_lo[tid] = (__bf16)(v - (float)hi);
}

// ---------------- kA: pre-convert node features to bf16 [NN][128] ----------------
__global__ void kA_conv(const float* __restrict__ h_re, const float* __restrict__ h_im,
                        __bf16* __restrict__ Ahi) {
    int tid = blockIdx.x * blockDim.x + threadIdx.x;
    if (tid >= NN * 128) return;
    int n = tid >> 7, k = tid & 127;
    float v = (k < 64) ? h_re[n * 64 + k] : h_im[n * 64 + (k - 64)];
    Ahi[tid] = (__bf16)v;
}

// ---------------- K1_ws: weights-stationary MFMA GEMM (2 products, 2-deep prefetch) ----
__global__ __launch_bounds__(256) void k1_ws(
    const __bf16* __restrict__ Ahi,                                      // [NN][128]
    const __bf16* __restrict__ Bt_hi, const __bf16* __restrict__ Bt_lo,  // [1024][128]
    unsigned* __restrict__ Whb, unsigned* __restrict__ Qhb) {
    int w = threadIdx.x >> 6, l = threadIdx.x & 63;
    int r = l & 15, g = l >> 4;
    int cls = blockIdx.x & 7;
    int chunk = blockIdx.x >> 3;
    int mh = cls >> 1, mat = cls & 1;
    int c0 = mh * 256 + mat * 128 + w * 16;
    int nbase = chunk * 256;
    unsigned* Out = mat ? Qhb : Whb;

    bf16x8 Wh_[2][4], Wl_[2][4];
#pragma unroll
    for (int t = 0; t < 2; ++t)
#pragma unroll
        for (int ch = 0; ch < 4; ++ch) {
            int boff = (c0 + t * 64 + r) * 128 + ch * 32 + g * 8;
            Wh_[t][ch] = *(const bf16x8*)(Bt_hi + boff);
            Wl_[t][ch] = *(const bf16x8*)(Bt_lo + boff);
        }

    bf16x8 N[3][4];
#pragma unroll
    for (int p = 0; p < 2; ++p) {
        int nc = min(nbase + p * 16 + r, NN - 1);
#pragma unroll
        for (int ch = 0; ch < 4; ++ch)
            N[p][ch] = *(const bf16x8*)(Ahi + nc * 128 + ch * 32 + g * 8);
    }

#pragma unroll
    for (int nt = 0; nt < 16; ++nt) {
        const int cur = nt % 3;
        if (nt + 2 < 16) {
            const int nxt = (nt + 2) % 3;
            int nc = min(nbase + (nt + 2) * 16 + r, NN - 1);
#pragma unroll
            for (int ch = 0; ch < 4; ++ch)
                N[nxt][ch] = *(const bf16x8*)(Ahi + nc * 128 + ch * 32 + g * 8);
        }
        f32x4 a0 = {0.f, 0.f, 0.f, 0.f}, a1 = {0.f, 0.f, 0.f, 0.f};
#pragma unroll
        for (int ch = 0; ch < 4; ++ch) {
            a0 = __builtin_amdgcn_mfma_f32_16x16x32_bf16(Wh_[0][ch], N[cur][ch], a0, 0, 0, 0);
            a1 = __builtin_amdgcn_mfma_f32_16x16x32_bf16(Wh_[1][ch], N[cur][ch], a1, 0, 0, 0);
            a0 = __builtin_amdgcn_mfma_f32_16x16x32_bf16(Wl_[0][ch], N[cur][ch], a0, 0, 0, 0);
            a1 = __builtin_amdgcn_mfma_f32_16x16x32_bf16(Wl_[1][ch], N[cur][ch], a1, 0, 0, 0);
        }
        int n = nbase + nt * 16 + r;
        if (n < NN) {
            uint4 u;
            u.x = pack_bf16c(a0[0], a1[0]);
            u.y = pack_bf16c(a0[1], a1[1]);
            u.z = pack_bf16c(a0[2], a1[2]);
            u.w = pack_bf16c(a0[3], a1[3]);
            *(uint4*)&Out[(n * HEADS + mh) * DIM + (c0 & 63) + g * 4] = u;
        }
    }
}

// ---------------- CSR build ----------------
__global__ void k2a_count(const int* __restrict__ dst, int* __restrict__ counts) {
    int e = blockIdx.x * blockDim.x + threadIdx.x;
    if (e < NE) atomicAdd(&counts[dst[e]], 1);
}

__global__ __launch_bounds__(1024) void k2b_scan(const int* __restrict__ counts,
                                                 int* __restrict__ row_ptr, int* __restrict__ cursor) {
    __shared__ int buf[1024];
    int t = threadIdx.x;
    const int CH = (NN + 1023) / 1024;  // 49
    int i0 = t * CH;
    int i1 = min(i0 + CH, NN);
    int sum = 0;
    for (int i = i0; i < i1; ++i) sum += counts[i];
    buf[t] = sum;
    __syncthreads();
    for (int off = 1; off < 1024; off <<= 1) {
        int x = 0;
        if (t >= off) x = buf[t - off];
        __syncthreads();
        buf[t] += x;
        __syncthreads();
    }
    int run = buf[t] - sum;
    for (int i = i0; i < i1; ++i) { row_ptr[i] = run; cursor[i] = run; run += counts[i]; }
    if (t == 1023) row_ptr[NN] = buf[1023];
}

__global__ void k2c_fill(const int* __restrict__ src, const int* __restrict__ dst,
                         int* __restrict__ cursor, int* __restrict__ sorted_src) {
    int e = blockIdx.x * blockDim.x + threadIdx.x;
    if (e < NE) {
        int pos = atomicAdd(&cursor[dst[e]], 1);
        sorted_src[pos] = src[e];
    }
}

// ---------------- K_main: 1 node/wave (64-thr block), 2 edges via 32-lane halves,
//                  8 lanes per head, 8 dims/lane, 3-stage reduce --------------------------
__global__ __launch_bounds__(64) void k_main(
    const float* __restrict__ h_re, const float* __restrict__ h_im,
    const __bf16* __restrict__ Ahi,          // [NN][128] bf16 (imag at +64)
    const uint4* __restrict__ Whb, const uint4* __restrict__ Qhb,
    const int* __restrict__ row_ptr, const int* __restrict__ sorted_src,
    __bf16* __restrict__ Sb, float2* __restrict__ T_out) {
    int lane = threadIdx.x;
    int e = lane >> 5;           // half (edge slot)
    int g = (lane >> 3) & 3;     // head
    int l = lane & 7;            // dim block of 8
    int n = blockIdx.x;
    int d0 = l * 8;

    float hre[8], him[8], qre[8], qim[8];
    {
        float4 a0 = *(const float4*)(h_re + n * DIM + d0);
        float4 a1 = *(const float4*)(h_re + n * DIM + d0 + 4);
        float4 b0 = *(const float4*)(h_im + n * DIM + d0);
        float4 b1 = *(const float4*)(h_im + n * DIM + d0 + 4);
        hre[0] = a0.x; hre[1] = a0.y; hre[2] = a0.z; hre[3] = a0.w;
        hre[4] = a1.x; hre[5] = a1.y; hre[6] = a1.z; hre[7] = a1.w;
        him[0] = b0.x; him[1] = b0.y; him[2] = b0.z; him[3] = b0.w;
        him[4] = b1.x; him[5] = b1.y; him[6] = b1.z; him[7] = b1.w;
        const unsigned* qp = (const unsigned*)Qhb + (n * HEADS + g) * DIM + d0;
        uint4 q0 = *(const uint4*)qp;
        uint4 q1 = *(const uint4*)(qp + 4);
        unsigned qw[8] = {q0.x, q0.y, q0.z, q0.w, q1.x, q1.y, q1.z, q1.w};
#pragma unroll
        for (int j = 0; j < 8; ++j) { qre[j] = bf_lo(qw[j]); qim[j] = bf_hi(qw[j]); }
    }
    // t = conj(Qh).h ; norm2 = |h|^2 (8-lane group reduce; both halves identical)
    float tr = 0.f, ti = 0.f, nr = 0.f;
#pragma unroll
    for (int j = 0; j < 8; ++j) {
        tr += qre[j] * hre[j] + qim[j] * him[j];
        ti += qre[j] * him[j] - qim[j] * hre[j];
        nr += hre[j] * hre[j] + him[j] * him[j];
    }
#pragma unroll
    for (int off = 1; off < 8; off <<= 1) {
        tr += __shfl_xor(tr, off, 64);
        ti += __shfl_xor(ti, off, 64);
        nr += __shfl_xor(nr, off, 64);
    }
    float2 tnm = make_float2(tr, ti);
    float inv_n2 = 1.0f / fmaxf(nr, 1e-6f);

    int beg = row_ptr[n], end = row_ptr[n + 1];
    float m_run = -1e30f, l_run = 0.f;
    float Sr[8] = {0, 0, 0, 0, 0, 0, 0, 0}, Si[8] = {0, 0, 0, 0, 0, 0, 0, 0};
    float Tr = 0.f, Ti = 0.f;

    // per-half edge buffers — ZERO-INITIALIZED: invalid slots compute with zeros,
    // never garbage (0*NaN would poison the cross-half merge).
    float4 cR0 = make_float4(0, 0, 0, 0), cR1 = cR0, pR0 = cR0, pR1 = cR0;
    uint4 cIm = make_uint4(0, 0, 0, 0), cW0 = cIm, cW1 = cIm;
    uint4 pIm = cIm, pW0 = cIm, pW1 = cIm;
    auto ldE = [&](int idx, float4& r0_, float4& r1_, uint4& im_, uint4& w0_, uint4& w1_) {
        int s = sorted_src[idx];
        r0_ = *(const float4*)(h_re + s * DIM + d0);
        r1_ = *(const float4*)(h_re + s * DIM + d0 + 4);
        im_ = *(const uint4*)(Ahi + s * 128 + 64 + d0);
        const unsigned* wp = (const unsigned*)Whb + (s * HEADS + g) * DIM + d0;
        w0_ = *(const uint4*)wp;
        w1_ = *(const uint4*)(wp + 4);
    };
    if (beg + e < end) ldE(beg + e, cR0, cR1, cIm, cW0, cW1);
    if (beg + 2 + e < end) ldE(beg + 2 + e, pR0, pR1, pIm, pW0, pW1);

    for (int pos = beg; pos < end; pos += 2) {
        bool valid = (pos + e) < end;
        float csr[8] = {cR0.x, cR0.y, cR0.z, cR0.w, cR1.x, cR1.y, cR1.z, cR1.w};
        float csi[8];
        {
            unsigned iw[4] = {cIm.x, cIm.y, cIm.z, cIm.w};
#pragma unroll
            for (int k = 0; k < 4; ++k) { csi[2 * k] = bf_lo(iw[k]); csi[2 * k + 1] = bf_hi(iw[k]); }
        }
        float wr[8], wi[8];
        {
            unsigned ww[8] = {cW0.x, cW0.y, cW0.z, cW0.w, cW1.x, cW1.y, cW1.z, cW1.w};
#pragma unroll
            for (int j = 0; j < 8; ++j) { wr[j] = bf_lo(ww[j]); wi[j] = bf_hi(ww[j]); }
        }
        // rotate buffers + prefetch 2 iterations (4 edges) ahead
        cR0 = pR0; cR1 = pR1; cIm = pIm; cW0 = pW0; cW1 = pW1;
        if (pos + 4 + e < end) ldE(pos + 4 + e, pR0, pR1, pIm, pW0, pW1);
        else { pR0 = make_float4(0, 0, 0, 0); pR1 = pR0; pIm = make_uint4(0, 0, 0, 0); pW0 = pIm; pW1 = pIm; }

        float r0 = 0, r1 = 0, r2 = 0, r3 = 0, r4 = 0;
#pragma unroll
        for (int j = 0; j < 8; ++j) {
            r0 += hre[j] * wr[j] + him[j] * wi[j];
            r1 += hre[j] * wi[j] - him[j] * wr[j];
            r2 += qre[j] * wr[j] + qim[j] * wi[j];
            r3 += qre[j] * wi[j] - qim[j] * wr[j];
            r4 += hre[j] * csr[j];
        }
#pragma unroll
        for (int off = 1; off < 8; off <<= 1) {
            r0 += __shfl_xor(r0, off, 64);
            r1 += __shfl_xor(r1, off, 64);
            r2 += __shfl_xor(r2, off, 64);
            r3 += __shfl_xor(r3, off, 64);
            r4 += __shfl_xor(r4, off, 64);
        }
        float sg = (r4 > 0.f) ? 1.f : ((r4 < 0.f) ? 0.f : 0.5f);
        float cre = SIC * r0 * inv_n2;
        float cim = SIC * r1 * inv_n2;
        float sre = r2 - (cre * tnm.x - cim * tnm.y);
        float sim_ = r3 - (cre * tnm.y + cim * tnm.x);
        float logit = sqrtf(sre * sre + sim_ * sim_) * 0.125f;
        if (!valid) logit = -1e30f;
        float lother = __shfl_xor(logit, 32, 64);
        float mnew = fmaxf(m_run, fmaxf(logit, lother));
        float f = __expf(m_run - mnew);
        float ex = valid ? __expf(logit - mnew) : 0.f;
        float wgt = ex * sg;
        l_run = l_run * f + ex;
#pragma unroll
        for (int j = 0; j < 8; ++j) {
            Sr[j] = Sr[j] * f + wgt * csr[j];
            Si[j] = Si[j] * f + wgt * csi[j];
        }
        Tr = Tr * f + wgt * cre;
        Ti = Ti * f + wgt * cim;
        m_run = mnew;
    }

    // merge the two halves (lane l and l+32 hold same (head, dims))
#pragma unroll
    for (int j = 0; j < 8; ++j) {
        Sr[j] += __shfl_xor(Sr[j], 32, 64);
        Si[j] += __shfl_xor(Si[j], 32, 64);
    }
    l_run += __shfl_xor(l_run, 32, 64);
    Tr += __shfl_xor(Tr, 32, 64);
    Ti += __shfl_xor(Ti, 32, 64);

    float inv = 1.0f / (l_run + 1e-16f);
    if (e == 0) {
        bf16x8 s0, s1;
#pragma unroll
        for (int j = 0; j < 4; ++j) {
            s0[2 * j] = (__bf16)(Sr[j] * inv);     s0[2 * j + 1] = (__bf16)(Si[j] * inv);
            s1[2 * j] = (__bf16)(Sr[j + 4] * inv); s1[2 * j + 1] = (__bf16)(Si[j + 4] * inv);
        }
        __bf16* sp = Sb + n * 512 + g * 128 + d0 * 2;
        *(bf16x8*)sp = s0;
        *(bf16x8*)(sp + 8) = s1;
        if (l == 0) T_out[n * HEADS + g] = make_float2(Tr * inv, Ti * inv);
    }
}

// ---------------- K5_ws: nodes-stationary MFMA GEMM + fused NodeNorm/ModReLU ----------
__global__ __launch_bounds__(256) void k5_ws(
    const float* __restrict__ h_re, const float* __restrict__ h_im,
    const __bf16* __restrict__ Sb,   // [NN][512]
    const float2* __restrict__ T_in,
    const __bf16* __restrict__ B2_hi, const __bf16* __restrict__ B2_lo,  // [128][512]
    const float* __restrict__ gate_raw, const float* __restrict__ modrelu_b,
    float2* __restrict__ out) {
    int w = threadIdx.x >> 6, l = threadIdx.x & 63;
    int n0 = blockIdx.x * 64 + w * 16;
    if (n0 >= NN) return;
    int r = l & 15, g = l >> 4;
    int nodeA = min(n0 + r, NN - 1);

    bf16x8 A_[16];
#pragma unroll
    for (int ch = 0; ch < 16; ++ch)
        A_[ch] = *(const bf16x8*)(Sb + nodeA * 512 + ch * 32 + g * 8);

    bf16x8 Bh[8], Bl[8];
#pragma unroll
    for (int s = 0; s < 8; ++s) {
        int boff = r * 512 + s * 32 + g * 8;
        Bh[s] = *(const bf16x8*)(B2_hi + boff);
        Bl[s] = *(const bf16x8*)(B2_lo + boff);
    }

    f32x4 acc[8];
#pragma unroll
    for (int t = 0; t < 8; ++t) acc[t] = {0.f, 0.f, 0.f, 0.f};

#pragma unroll
    for (int nt = 0; nt < 8; ++nt) {
#pragma unroll
        for (int ch = 0; ch < 16; ++ch) {
            const int slot = ch & 7;
            bf16x8 bh = Bh[slot], bl = Bl[slot];
            int fl = nt * 16 + ch + 8;
            if (fl < 128) {
                int fnt = fl >> 4, fch = fl & 15;
                int boff = (fnt * 16 + r) * 512 + fch * 32 + g * 8;
                Bh[slot] = *(const bf16x8*)(B2_hi + boff);
                Bl[slot] = *(const bf16x8*)(B2_lo + boff);
            }
            acc[nt] = __builtin_amdgcn_mfma_f32_16x16x32_bf16(A_[ch], bh, acc[nt], 0, 0, 0);
            acc[nt] = __builtin_amdgcn_mfma_f32_16x16x32_bf16(A_[ch], bl, acc[nt], 0, 0, 0);
        }
    }

    float gate = 1.0f / (1.0f + expf(-gate_raw[0]));
    float bo[4];
#pragma unroll
    for (int q = 0; q < 4; ++q) bo[q] = modrelu_b[q * 16 + r];

#pragma unroll
    for (int j = 0; j < 4; ++j) {
        int n = n0 + g * 4 + j;
        int nc = min(n, NN - 1);
        float2 Ts = make_float2(0.f, 0.f);
#pragma unroll
        for (int m = 0; m < HEADS; ++m) {
            float2 tv = T_in[nc * HEADS + m];
            Ts.x += tv.x; Ts.y += tv.y;
        }
        float xr_[4], xi_[4];
        float sr = 0.f, si = 0.f, qr = 0.f, qi = 0.f;
#pragma unroll
        for (int q = 0; q < 4; ++q) {
            int o = q * 16 + r;
            float hr = h_re[nc * DIM + o];
            float hi = h_im[nc * DIM + o];
            float nre = hr + acc[q][j]     - gate * (Ts.x * hr - Ts.y * hi);
            float nim = hi + acc[q + 4][j] - gate * (Ts.x * hi + Ts.y * hr);
            xr_[q] = nre; xi_[q] = nim;
            sr += nre; si += nim; qr += nre * nre; qi += nim * nim;
        }
#pragma unroll
        for (int off = 1; off < 16; off <<= 1) {
            sr += __shfl_xor(sr, off, 64);
            si += __shfl_xor(si, off, 64);
            qr += __shfl_xor(qr, off, 64);
            qi += __shfl_xor(qi, off, 64);
        }
        float mean_r = sr * (1.f / DIM), mean_i = si * (1.f / DIM);
        float var_r = (qr - DIM * mean_r * mean_r) * (1.f / (DIM - 1));
        float var_i = (qi - DIM * mean_i * mean_i) * (1.f / (DIM - 1));
        float std_r = fmaxf(sqrtf(fmaxf(var_r, 0.f)), 1e-5f);
        float std_i = fmaxf(sqrtf(fmaxf(var_i, 0.f)), 1e-5f);
        if (n < NN) {
#pragma unroll
            for (int q = 0; q < 4; ++q) {
                float xr = (xr_[q] - mean_r) / std_r;
                float xi = (xi_[q] - mean_i) / std_i;
                float mag = fmaxf(sqrtf(xr * xr + xi * xi), 1e-6f);
                float gg = fmaxf(mag + bo[q], 0.f);
                float sc = gg / mag;
                out[n * DIM + q * 16 + r] = make_float2(xr * sc, xi * sc);
            }
        }
    }
}

extern "C" void kernel_launch(void* const* d_in, const int* in_sizes, int n_in,
                              void* d_out, int out_size, void* d_ws, size_t ws_size,
                              hipStream_t stream) {
    const float* h_re = (const float*)d_in[0];
    const float* h_im = (const float*)d_in[1];
    const float* W_re = (const float*)d_in[2];
    const float* W_im = (const float*)d_in[3];
    const float* Q_re = (const float*)d_in[4];
    const float* Q_im = (const float*)d_in[5];
    const float* gate_raw = (const float*)d_in[6];
    const float* b = (const float*)d_in[7];
    const int* src = (const int*)d_in[8];
    const int* dst = (const int*)d_in[9];

    char* ws = (char*)d_ws;
    size_t off = 0;
    auto alloc = [&](size_t bytes) {
        void* p = ws + off;
        off = (off + bytes + 255) & ~(size_t)255;
        return p;
    };
    __bf16* Bt_hi = (__bf16*)alloc((size_t)1024 * 128 * sizeof(__bf16));
    __bf16* Bt_lo = (__bf16*)alloc((size_t)1024 * 128 * sizeof(__bf16));
    __bf16* B2_hi = (__bf16*)alloc((size_t)128 * 512 * sizeof(__bf16));
    __bf16* B2_lo = (__bf16*)alloc((size_t)128 * 512 * sizeof(__bf16));
    __bf16* Ahi = (__bf16*)alloc((size_t)NN * 128 * sizeof(__bf16));
    unsigned* Whb = (unsigned*)alloc((size_t)NN * HEADS * DIM * sizeof(unsigned));
    unsigned* Qhb = (unsigned*)alloc((size_t)NN * HEADS * DIM * sizeof(unsigned));
    __bf16* Sb = (__bf16*)alloc((size_t)NN * 512 * sizeof(__bf16));
    float2* T_buf = (float2*)alloc((size_t)NN * HEADS * sizeof(float2));
    int* counts = (int*)alloc((size_t)NN * sizeof(int));
    int* row_ptr = (int*)alloc((size_t)(NN + 1) * sizeof(int));
    int* cursor = (int*)alloc((size_t)NN * sizeof(int));
    int* sorted_src = (int*)alloc((size_t)NE * sizeof(int));

    hipMemsetAsync(counts, 0, (size_t)NN * sizeof(int), stream);
    k0b_build<<<(1024 * 128 + 255) / 256, 256, 0, stream>>>(W_re, W_im, Q_re, Q_im, Bt_hi, Bt_lo);
    k0c_build<<<(128 * 512 + 255) / 256, 256, 0, stream>>>(W_re, W_im, B2_hi, B2_lo);
    kA_conv<<<(NN * 128 + 255) / 256, 256, 0, stream>>>(h_re, h_im, Ahi);
    k1_ws<<<8 * ((NN + 255) / 256), 256, 0, stream>>>(Ahi, Bt_hi, Bt_lo, Whb, Qhb);
    k2a_count<<<(NE + 255) / 256, 256, 0, stream>>>(dst, counts);
    k2b_scan<<<1, 1024, 0, stream>>>(counts, row_ptr, cursor);
    k2c_fill<<<(NE + 255) / 256, 256, 0, stream>>>(src, dst, cursor, sorted_src);
    k_main<<<NN, 64, 0, stream>>>(h_re, h_im, Ahi, (const uint4*)Whb, (const uint4*)Qhb,
                                  row_ptr, sorted_src, Sb, T_buf);
    k5_ws<<<(NN + 63) / 64, 256, 0, stream>>>(h_re, h_im, Sb, T_buf, B2_hi, B2_lo,
                                              gate_raw, b, (float2*)d_out);
}

// Round 8
// 416.150 us; speedup vs baseline: 2.7865x; 1.3169x over previous
//
#include <hip/hip_runtime.h>
#include <hip/hip_bf16.h>
#include <math.h>

#define NN 50000
#define NE 400000
#define DIM 64
#define HEADS 4
#define SIC 0.5f

typedef _Float16 f16x8 __attribute__((ext_vector_type(8)));
typedef _Float16 f16x2 __attribute__((ext_vector_type(2)));
typedef float f32x4 __attribute__((ext_vector_type(4)));

__device__ __forceinline__ unsigned pack_f16c(float re, float im) {
    f16x2 p; p[0] = (_Float16)re; p[1] = (_Float16)im;
    return __builtin_bit_cast(unsigned, p);
}

// (-b, a) from (a, b): swap halves, negate new low half
__device__ __forceinline__ f16x2 swapneg(f16x2 v) {
    unsigned u = __builtin_bit_cast(unsigned, v);
    u = ((u >> 16) | (u << 16)) ^ 0x8000u;
    return __builtin_bit_cast(f16x2, u);
}

// sum over 8-lane group via DPP (no LDS): xor1, xor2, then half-row mirror
__device__ __forceinline__ float dpp_red8(float x) {
    int xi = __builtin_bit_cast(int, x);
    x += __builtin_bit_cast(float, __builtin_amdgcn_update_dpp(0, xi, 0xB1, 0xF, 0xF, true));
    xi = __builtin_bit_cast(int, x);
    x += __builtin_bit_cast(float, __builtin_amdgcn_update_dpp(0, xi, 0x4E, 0xF, 0xF, true));
    xi = __builtin_bit_cast(int, x);
    x += __builtin_bit_cast(float, __builtin_amdgcn_update_dpp(0, xi, 0x141, 0xF, 0xF, true));
    return x;
}

// ---------------- K0: build both weight tables (f16 single precision tier) -------------
// Btf[c][k], [1024][128]: c = mh*256 + mat*128 + comp*64 + o ; k<64 re-input, k>=64 im
// B2f[c2][k2], [128][512]: k2 = m*128 + i*2 + cin ; c2 = comp_out*64 + o
__global__ void k0_build(const float* __restrict__ Wre, const float* __restrict__ Wim,
                         const float* __restrict__ Qre, const float* __restrict__ Qim,
                         _Float16* __restrict__ Btf, _Float16* __restrict__ B2f) {
    int tid = blockIdx.x * blockDim.x + threadIdx.x;
    if (tid < 1024 * 128) {
        int c = tid >> 7, k = tid & 127;
        int mh = c >> 8, cm = c & 255;
        int mat = cm >> 7, comp = (cm >> 6) & 1, o = cm & 63;
        int part = k >> 6, i = k & 63;
        const float* Mre = mat ? Qre : Wre;
        const float* Mim = mat ? Qim : Wim;
        int widx = (mh * DIM + o) * DIM + i;
        float v;
        if (comp == 0) v = part ? -Mim[widx] : Mre[widx];
        else           v = part ?  Mre[widx] : Mim[widx];
        Btf[tid] = (_Float16)v;
    } else if (tid < 1024 * 128 + 128 * 512) {
        int t2 = tid - 1024 * 128;
        int c_out = t2 >> 9, k = t2 & 511;
        int comp_out = c_out >> 6, o = c_out & 63;
        int m = k >> 7, cin = k & 1, i = (k >> 1) & 63;
        int widx = (m * DIM + o) * DIM + i;
        float v;
        if (cin == 0) v = comp_out ? Wim[widx] : Wre[widx];
        else          v = comp_out ? Wre[widx] : -Wim[widx];
        B2f[t2] = (_Float16)v;
    }
}

// ---------------- kA: node features to f16 [NN][128] ----------------
__global__ void kA_conv(const float* __restrict__ h_re, const float* __restrict__ h_im,
                        _Float16* __restrict__ Af16) {
    int tid = blockIdx.x * blockDim.x + threadIdx.x;
    if (tid >= NN * 128) return;
    int n = tid >> 7, k = tid & 127;
    float v = (k < 64) ? h_re[n * 64 + k] : h_im[n * 64 + (k - 64)];
    Af16[tid] = (_Float16)v;
}

// ---------------- K1_ws: weights-stationary f16 MFMA GEMM (single product) -------------
__global__ __launch_bounds__(256) void k1_ws(
    const _Float16* __restrict__ Af16,                // [NN][128]
    const _Float16* __restrict__ Btf,                 // [1024][128]
    unsigned* __restrict__ Whf, unsigned* __restrict__ Qhf) {
    int w = threadIdx.x >> 6, l = threadIdx.x & 63;
    int r = l & 15, g = l >> 4;
    int cls = blockIdx.x & 7;
    int chunk = blockIdx.x >> 3;
    int mh = cls >> 1, mat = cls & 1;
    int c0 = mh * 256 + mat * 128 + w * 16;
    int nbase = chunk * 256;
    unsigned* Out = mat ? Qhf : Whf;

    f16x8 Wf[2][4];
#pragma unroll
    for (int t = 0; t < 2; ++t)
#pragma unroll
        for (int ch = 0; ch < 4; ++ch)
            Wf[t][ch] = *(const f16x8*)(Btf + (c0 + t * 64 + r) * 128 + ch * 32 + g * 8);

    f16x8 N[3][4];
#pragma unroll
    for (int p = 0; p < 2; ++p) {
        int nc = min(nbase + p * 16 + r, NN - 1);
#pragma unroll
        for (int ch = 0; ch < 4; ++ch)
            N[p][ch] = *(const f16x8*)(Af16 + nc * 128 + ch * 32 + g * 8);
    }

#pragma unroll
    for (int nt = 0; nt < 16; ++nt) {
        const int cur = nt % 3;
        if (nt + 2 < 16) {
            const int nxt = (nt + 2) % 3;
            int nc = min(nbase + (nt + 2) * 16 + r, NN - 1);
#pragma unroll
            for (int ch = 0; ch < 4; ++ch)
                N[nxt][ch] = *(const f16x8*)(Af16 + nc * 128 + ch * 32 + g * 8);
        }
        f32x4 a0 = {0.f, 0.f, 0.f, 0.f}, a1 = {0.f, 0.f, 0.f, 0.f};
#pragma unroll
        for (int ch = 0; ch < 4; ++ch) {
            a0 = __builtin_amdgcn_mfma_f32_16x16x32_f16(Wf[0][ch], N[cur][ch], a0, 0, 0, 0);
            a1 = __builtin_amdgcn_mfma_f32_16x16x32_f16(Wf[1][ch], N[cur][ch], a1, 0, 0, 0);
        }
        int n = nbase + nt * 16 + r;
        if (n < NN) {
            uint4 u;
            u.x = pack_f16c(a0[0], a1[0]);
            u.y = pack_f16c(a0[1], a1[1]);
            u.z = pack_f16c(a0[2], a1[2]);
            u.w = pack_f16c(a0[3], a1[3]);
            *(uint4*)&Out[(n * HEADS + mh) * DIM + (c0 & 63) + g * 4] = u;
        }
    }
}

// ---------------- CSR build ----------------
__global__ void k2a_count(const int* __restrict__ dst, int* __restrict__ counts) {
    int e = blockIdx.x * blockDim.x + threadIdx.x;
    if (e < NE) atomicAdd(&counts[dst[e]], 1);
}

__global__ __launch_bounds__(1024) void k2b_scan(const int* __restrict__ counts,
                                                 int* __restrict__ row_ptr, int* __restrict__ cursor) {
    __shared__ int buf[1024];
    int t = threadIdx.x;
    const int CH = (NN + 1023) / 1024;  // 49
    int i0 = t * CH;
    int i1 = min(i0 + CH, NN);
    int sum = 0;
    for (int i = i0; i < i1; ++i) sum += counts[i];
    buf[t] = sum;
    __syncthreads();
    for (int off = 1; off < 1024; off <<= 1) {
        int x = 0;
        if (t >= off) x = buf[t - off];
        __syncthreads();
        buf[t] += x;
        __syncthreads();
    }
    int run = buf[t] - sum;
    for (int i = i0; i < i1; ++i) { row_ptr[i] = run; cursor[i] = run; run += counts[i]; }
    if (t == 1023) row_ptr[NN] = buf[1023];
}

__global__ void k2c_fill(const int* __restrict__ src, const int* __restrict__ dst,
                         int* __restrict__ cursor, int* __restrict__ sorted_src) {
    int e = blockIdx.x * blockDim.x + threadIdx.x;
    if (e < NE) {
        int pos = atomicAdd(&cursor[dst[e]], 1);
        sorted_src[pos] = src[e];
    }
}

// ---------------- K_main: 1 node/wave, 2 edges via 32-lane halves, fdot2 + DPP,
//                  no-max online softmax (logits >= 0, bounded => exp safe) -------------
__global__ __launch_bounds__(64) void k_main(
    const float* __restrict__ h_re, const float* __restrict__ h_im,
    const _Float16* __restrict__ Af16,       // [NN][128] (imag at +64)
    const uint4* __restrict__ Whf, const uint4* __restrict__ Qhf,  // f16 pairs
    const int* __restrict__ row_ptr, const int* __restrict__ sorted_src,
    _Float16* __restrict__ Sb, float2* __restrict__ T_out) {
    int lane = threadIdx.x;
    int e = lane >> 5;           // half (edge slot)
    int g = (lane >> 3) & 3;     // head
    int l = lane & 7;            // dim block of 8
    int n = blockIdx.x;
    int d0 = l * 8;

    float hre[8];
    f16x2 hd2[8], hdn2[8], qh2[8], qhn2[8];
    float tr = 0.f, ti = 0.f, nr = 0.f;
    {
        float4 a0 = *(const float4*)(h_re + n * DIM + d0);
        float4 a1 = *(const float4*)(h_re + n * DIM + d0 + 4);
        float4 b0 = *(const float4*)(h_im + n * DIM + d0);
        float4 b1 = *(const float4*)(h_im + n * DIM + d0 + 4);
        float hrev[8] = {a0.x, a0.y, a0.z, a0.w, a1.x, a1.y, a1.z, a1.w};
        float himv[8] = {b0.x, b0.y, b0.z, b0.w, b1.x, b1.y, b1.z, b1.w};
        const unsigned* qp = (const unsigned*)Qhf + (n * HEADS + g) * DIM + d0;
        uint4 q0 = *(const uint4*)qp;
        uint4 q1 = *(const uint4*)(qp + 4);
        unsigned qw[8] = {q0.x, q0.y, q0.z, q0.w, q1.x, q1.y, q1.z, q1.w};
#pragma unroll
        for (int j = 0; j < 8; ++j) {
            hre[j] = hrev[j];
            hd2[j][0] = (_Float16)hrev[j]; hd2[j][1] = (_Float16)himv[j];
            hdn2[j] = swapneg(hd2[j]);
            f16x2 q2 = __builtin_bit_cast(f16x2, qw[j]);
            qh2[j] = q2;
            qhn2[j] = swapneg(q2);
            float qre = (float)q2[0], qim = (float)q2[1];
            tr += qre * hrev[j] + qim * himv[j];
            ti += qre * himv[j] - qim * hrev[j];
            nr += hrev[j] * hrev[j] + himv[j] * himv[j];
        }
    }
    tr = dpp_red8(tr); ti = dpp_red8(ti); nr = dpp_red8(nr);
    float2 tnm = make_float2(tr, ti);
    float inv_n2 = 1.0f / fmaxf(nr, 1e-6f);

    int beg = row_ptr[n], end = row_ptr[n + 1];
    float l_run = 0.f, Tr = 0.f, Ti = 0.f;
    float Sr[8] = {0, 0, 0, 0, 0, 0, 0, 0}, Si[8] = {0, 0, 0, 0, 0, 0, 0, 0};

    // per-half edge buffers — zero-init (invalid slots must compute with zeros, not garbage)
    float4 cR0 = make_float4(0, 0, 0, 0), cR1 = cR0, pR0 = cR0, pR1 = cR0;
    uint4 cIm = make_uint4(0, 0, 0, 0), cW0 = cIm, cW1 = cIm;
    uint4 pIm = cIm, pW0 = cIm, pW1 = cIm;
    auto ldE = [&](int idx, float4& r0_, float4& r1_, uint4& im_, uint4& w0_, uint4& w1_) {
        int s = sorted_src[idx];
        r0_ = *(const float4*)(h_re + s * DIM + d0);
        r1_ = *(const float4*)(h_re + s * DIM + d0 + 4);
        im_ = *(const uint4*)(Af16 + s * 128 + 64 + d0);
        const unsigned* wp = (const unsigned*)Whf + (s * HEADS + g) * DIM + d0;
        w0_ = *(const uint4*)wp;
        w1_ = *(const uint4*)(wp + 4);
    };
    if (beg + e < end) ldE(beg + e, cR0, cR1, cIm, cW0, cW1);
    if (beg + 2 + e < end) ldE(beg + 2 + e, pR0, pR1, pIm, pW0, pW1);

    for (int pos = beg; pos < end; pos += 2) {
        bool valid = (pos + e) < end;
        float csr[8] = {cR0.x, cR0.y, cR0.z, cR0.w, cR1.x, cR1.y, cR1.z, cR1.w};
        float csi[8];
        {
            unsigned iw[4] = {cIm.x, cIm.y, cIm.z, cIm.w};
#pragma unroll
            for (int k = 0; k < 4; ++k) {
                f16x2 p = __builtin_bit_cast(f16x2, iw[k]);
                csi[2 * k] = (float)p[0];
                csi[2 * k + 1] = (float)p[1];
            }
        }
        unsigned ww[8] = {cW0.x, cW0.y, cW0.z, cW0.w, cW1.x, cW1.y, cW1.z, cW1.w};
        // rotate + prefetch 2 iterations (4 edges) ahead
        cR0 = pR0; cR1 = pR1; cIm = pIm; cW0 = pW0; cW1 = pW1;
        if (pos + 4 + e < end) ldE(pos + 4 + e, pR0, pR1, pIm, pW0, pW1);
        else { pR0 = make_float4(0, 0, 0, 0); pR1 = pR0; pIm = make_uint4(0, 0, 0, 0); pW0 = pIm; pW1 = pIm; }

        float r0 = 0, r1 = 0, r2 = 0, r3 = 0, r4 = 0;
#pragma unroll
        for (int j = 0; j < 8; ++j) {
            f16x2 w2 = __builtin_bit_cast(f16x2, ww[j]);
            r0 = __builtin_amdgcn_fdot2(w2, hd2[j], r0, false);
            r1 = __builtin_amdgcn_fdot2(w2, hdn2[j], r1, false);
            r2 = __builtin_amdgcn_fdot2(w2, qh2[j], r2, false);
            r3 = __builtin_amdgcn_fdot2(w2, qhn2[j], r3, false);
            r4 = fmaf(hre[j], csr[j], r4);
        }
        r0 = dpp_red8(r0); r1 = dpp_red8(r1); r2 = dpp_red8(r2);
        r3 = dpp_red8(r3); r4 = dpp_red8(r4);

        float sg = (r4 > 0.f) ? 1.f : ((r4 < 0.f) ? 0.f : 0.5f);
        float cre = SIC * r0 * inv_n2;
        float cim = SIC * r1 * inv_n2;
        float sre = r2 - (cre * tnm.x - cim * tnm.y);
        float sim_ = r3 - (cre * tnm.y + cim * tnm.x);
        float logit = sqrtf(sre * sre + sim_ * sim_) * 0.125f;
        float ex = valid ? __expf(logit) : 0.f;
        float wgt = ex * sg;
        l_run += ex;
#pragma unroll
        for (int j = 0; j < 8; ++j) {
            Sr[j] = fmaf(wgt, csr[j], Sr[j]);
            Si[j] = fmaf(wgt, csi[j], Si[j]);
        }
        Tr = fmaf(wgt, cre, Tr);
        Ti = fmaf(wgt, cim, Ti);
    }

    // merge the two halves (lane l and l+32 hold same (head, dims); same exp scale)
#pragma unroll
    for (int j = 0; j < 8; ++j) {
        Sr[j] += __shfl_xor(Sr[j], 32, 64);
        Si[j] += __shfl_xor(Si[j], 32, 64);
    }
    l_run += __shfl_xor(l_run, 32, 64);
    Tr += __shfl_xor(Tr, 32, 64);
    Ti += __shfl_xor(Ti, 32, 64);

    float inv = 1.0f / (l_run + 1e-16f);
    if (e == 0) {
        f16x8 s0, s1;
#pragma unroll
        for (int j = 0; j < 4; ++j) {
            s0[2 * j] = (_Float16)(Sr[j] * inv);     s0[2 * j + 1] = (_Float16)(Si[j] * inv);
            s1[2 * j] = (_Float16)(Sr[j + 4] * inv); s1[2 * j + 1] = (_Float16)(Si[j + 4] * inv);
        }
        _Float16* sp = Sb + n * 512 + g * 128 + d0 * 2;
        *(f16x8*)sp = s0;
        *(f16x8*)(sp + 8) = s1;
        if (l == 0) T_out[n * HEADS + g] = make_float2(Tr * inv, Ti * inv);
    }
}

// ---------------- K5_ws: nodes-stationary f16 MFMA GEMM + fused NodeNorm/ModReLU ------
__global__ __launch_bounds__(256) void k5_ws(
    const float* __restrict__ h_re, const float* __restrict__ h_im,
    const _Float16* __restrict__ Sb,   // [NN][512]
    const float2* __restrict__ T_in,
    const _Float16* __restrict__ B2f,  // [128][512]
    const float* __restrict__ gate_raw, const float* __restrict__ modrelu_b,
    float2* __restrict__ out) {
    int w = threadIdx.x >> 6, l = threadIdx.x & 63;
    int n0 = blockIdx.x * 64 + w * 16;
    if (n0 >= NN) return;
    int r = l & 15, g = l >> 4;
    int nodeA = min(n0 + r, NN - 1);

    f16x8 A_[16];
#pragma unroll
    for (int ch = 0; ch < 16; ++ch)
        A_[ch] = *(const f16x8*)(Sb + nodeA * 512 + ch * 32 + g * 8);

    f16x8 Bf[8];
#pragma unroll
    for (int s = 0; s < 8; ++s)
        Bf[s] = *(const f16x8*)(B2f + r * 512 + s * 32 + g * 8);

    f32x4 acc[8];
#pragma unroll
    for (int t = 0; t < 8; ++t) acc[t] = {0.f, 0.f, 0.f, 0.f};

#pragma unroll
    for (int nt = 0; nt < 8; ++nt) {
#pragma unroll
        for (int ch = 0; ch < 16; ++ch) {
            const int slot = ch & 7;
            f16x8 b = Bf[slot];
            int fl = nt * 16 + ch + 8;
            if (fl < 128) {
                int fnt = fl >> 4, fch = fl & 15;
                Bf[slot] = *(const f16x8*)(B2f + (fnt * 16 + r) * 512 + fch * 32 + g * 8);
            }
            acc[nt] = __builtin_amdgcn_mfma_f32_16x16x32_f16(A_[ch], b, acc[nt], 0, 0, 0);
        }
    }

    float gate = 1.0f / (1.0f + expf(-gate_raw[0]));
    float bo[4];
#pragma unroll
    for (int q = 0; q < 4; ++q) bo[q] = modrelu_b[q * 16 + r];

#pragma unroll
    for (int j = 0; j < 4; ++j) {
        int n = n0 + g * 4 + j;
        int nc = min(n, NN - 1);
        float2 Ts = make_float2(0.f, 0.f);
#pragma unroll
        for (int m = 0; m < HEADS; ++m) {
            float2 tv = T_in[nc * HEADS + m];
            Ts.x += tv.x; Ts.y += tv.y;
        }
        float xr_[4], xi_[4];
        float sr = 0.f, si = 0.f, qr = 0.f, qi = 0.f;
#pragma unroll
        for (int q = 0; q < 4; ++q) {
            int o = q * 16 + r;
            float hr = h_re[nc * DIM + o];
            float hi = h_im[nc * DIM + o];
            float nre = hr + acc[q][j]     - gate * (Ts.x * hr - Ts.y * hi);
            float nim = hi + acc[q + 4][j] - gate * (Ts.x * hi + Ts.y * hr);
            xr_[q] = nre; xi_[q] = nim;
            sr += nre; si += nim; qr += nre * nre; qi += nim * nim;
        }
#pragma unroll
        for (int off = 1; off < 16; off <<= 1) {
            sr += __shfl_xor(sr, off, 64);
            si += __shfl_xor(si, off, 64);
            qr += __shfl_xor(qr, off, 64);
            qi += __shfl_xor(qi, off, 64);
        }
        float mean_r = sr * (1.f / DIM), mean_i = si * (1.f / DIM);
        float var_r = (qr - DIM * mean_r * mean_r) * (1.f / (DIM - 1));
        float var_i = (qi - DIM * mean_i * mean_i) * (1.f / (DIM - 1));
        float std_r = fmaxf(sqrtf(fmaxf(var_r, 0.f)), 1e-5f);
        float std_i = fmaxf(sqrtf(fmaxf(var_i, 0.f)), 1e-5f);
        if (n < NN) {
#pragma unroll
            for (int q = 0; q < 4; ++q) {
                float xr = (xr_[q] - mean_r) / std_r;
                float xi = (xi_[q] - mean_i) / std_i;
                float mag = fmaxf(sqrtf(xr * xr + xi * xi), 1e-6f);
                float gg = fmaxf(mag + bo[q], 0.f);
                float sc = gg / mag;
                out[n * DIM + q * 16 + r] = make_float2(xr * sc, xi * sc);
            }
        }
    }
}

extern "C" void kernel_launch(void* const* d_in, const int* in_sizes, int n_in,
                              void* d_out, int out_size, void* d_ws, size_t ws_size,
                              hipStream_t stream) {
    const float* h_re = (const float*)d_in[0];
    const float* h_im = (const float*)d_in[1];
    const float* W_re = (const float*)d_in[2];
    const float* W_im = (const float*)d_in[3];
    const float* Q_re = (const float*)d_in[4];
    const float* Q_im = (const float*)d_in[5];
    const float* gate_raw = (const float*)d_in[6];
    const float* b = (const float*)d_in[7];
    const int* src = (const int*)d_in[8];
    const int* dst = (const int*)d_in[9];

    char* ws = (char*)d_ws;
    size_t off = 0;
    auto alloc = [&](size_t bytes) {
        void* p = ws + off;
        off = (off + bytes + 255) & ~(size_t)255;
        return p;
    };
    _Float16* Btf = (_Float16*)alloc((size_t)1024 * 128 * sizeof(_Float16));
    _Float16* B2f = (_Float16*)alloc((size_t)128 * 512 * sizeof(_Float16));
    _Float16* Af16 = (_Float16*)alloc((size_t)NN * 128 * sizeof(_Float16));
    unsigned* Whf = (unsigned*)alloc((size_t)NN * HEADS * DIM * sizeof(unsigned));
    unsigned* Qhf = (unsigned*)alloc((size_t)NN * HEADS * DIM * sizeof(unsigned));
    _Float16* Sb = (_Float16*)alloc((size_t)NN * 512 * sizeof(_Float16));
    float2* T_buf = (float2*)alloc((size_t)NN * HEADS * sizeof(float2));
    int* counts = (int*)alloc((size_t)NN * sizeof(int));
    int* row_ptr = (int*)alloc((size_t)(NN + 1) * sizeof(int));
    int* cursor = (int*)alloc((size_t)NN * sizeof(int));
    int* sorted_src = (int*)alloc((size_t)NE * sizeof(int));

    hipMemsetAsync(counts, 0, (size_t)NN * sizeof(int), stream);
    k0_build<<<(1024 * 128 + 128 * 512 + 255) / 256, 256, 0, stream>>>(W_re, W_im, Q_re, Q_im, Btf, B2f);
    kA_conv<<<(NN * 128 + 255) / 256, 256, 0, stream>>>(h_re, h_im, Af16);
    k1_ws<<<8 * ((NN + 255) / 256), 256, 0, stream>>>(Af16, Btf, Whf, Qhf);
    k2a_count<<<(NE + 255) / 256, 256, 0, stream>>>(dst, counts);
    k2b_scan<<<1, 1024, 0, stream>>>(counts, row_ptr, cursor);
    k2c_fill<<<(NE + 255) / 256, 256, 0, stream>>>(src, dst, cursor, sorted_src);
    k_main<<<NN, 64, 0, stream>>>(h_re, h_im, Af16, (const uint4*)Whf, (const uint4*)Qhf,
                                  row_ptr, sorted_src, Sb, T_buf);
    k5_ws<<<(NN + 63) / 64, 256, 0, stream>>>(h_re, h_im, Sb, T_buf, B2f,
                                              gate_raw, b, (float2*)d_out);
}

// Round 9
// 412.333 us; speedup vs baseline: 2.8123x; 1.0093x over previous
//
#include <hip/hip_runtime.h>
#include <hip/hip_bf16.h>
#include <math.h>

#define NN 50000
#define NE 400000
#define DIM 64
#define HEADS 4
#define SIC 0.5f

typedef _Float16 f16x8 __attribute__((ext_vector_type(8)));
typedef _Float16 f16x2 __attribute__((ext_vector_type(2)));
typedef float f32x4 __attribute__((ext_vector_type(4)));

__device__ __forceinline__ unsigned pack_f16c(float re, float im) {
    f16x2 p; p[0] = (_Float16)re; p[1] = (_Float16)im;
    return __builtin_bit_cast(unsigned, p);
}

// (-b, a) from (a, b): swap halves, negate new low half
__device__ __forceinline__ f16x2 swapneg(f16x2 v) {
    unsigned u = __builtin_bit_cast(unsigned, v);
    u = ((u >> 16) | (u << 16)) ^ 0x8000u;
    return __builtin_bit_cast(f16x2, u);
}

// sum over 8-lane group via DPP (no LDS): xor1, xor2, then half-row mirror
__device__ __forceinline__ float dpp_red8(float x) {
    int xi = __builtin_bit_cast(int, x);
    x += __builtin_bit_cast(float, __builtin_amdgcn_update_dpp(0, xi, 0xB1, 0xF, 0xF, true));
    xi = __builtin_bit_cast(int, x);
    x += __builtin_bit_cast(float, __builtin_amdgcn_update_dpp(0, xi, 0x4E, 0xF, 0xF, true));
    xi = __builtin_bit_cast(int, x);
    x += __builtin_bit_cast(float, __builtin_amdgcn_update_dpp(0, xi, 0x141, 0xF, 0xF, true));
    return x;
}

// ---------------- k_pre: fused weight tables + node f16 conversion + degree count ------
// Btf[c][k], [1024][128]: c = mh*256 + mat*128 + comp*64 + o ; k<64 re-input, k>=64 im
// B2f[c2][k2], [128][512]: k2 = m*128 + i*2 + cin ; c2 = comp_out*64 + o
// Af16[n][k]: k<64 re, k>=64 im
#define S0 (1024 * 128)
#define S1 (S0 + 128 * 512)
#define S2 (S1 + NN * 128)
#define S3 (S2 + NE)
__global__ void k_pre(const float* __restrict__ h_re, const float* __restrict__ h_im,
                      const float* __restrict__ Wre, const float* __restrict__ Wim,
                      const float* __restrict__ Qre, const float* __restrict__ Qim,
                      const int* __restrict__ dst,
                      _Float16* __restrict__ Btf, _Float16* __restrict__ B2f,
                      _Float16* __restrict__ Af16, int* __restrict__ counts) {
    int tid = blockIdx.x * blockDim.x + threadIdx.x;
    if (tid < S0) {
        int c = tid >> 7, k = tid & 127;
        int mh = c >> 8, cm = c & 255;
        int mat = cm >> 7, comp = (cm >> 6) & 1, o = cm & 63;
        int part = k >> 6, i = k & 63;
        const float* Mre = mat ? Qre : Wre;
        const float* Mim = mat ? Qim : Wim;
        int widx = (mh * DIM + o) * DIM + i;
        float v;
        if (comp == 0) v = part ? -Mim[widx] : Mre[widx];
        else           v = part ?  Mre[widx] : Mim[widx];
        Btf[tid] = (_Float16)v;
    } else if (tid < S1) {
        int t2 = tid - S0;
        int c_out = t2 >> 9, k = t2 & 511;
        int comp_out = c_out >> 6, o = c_out & 63;
        int m = k >> 7, cin = k & 1, i = (k >> 1) & 63;
        int widx = (m * DIM + o) * DIM + i;
        float v;
        if (cin == 0) v = comp_out ? Wim[widx] : Wre[widx];
        else          v = comp_out ? Wre[widx] : -Wim[widx];
        B2f[t2] = (_Float16)v;
    } else if (tid < S2) {
        int t2 = tid - S1;
        int n = t2 >> 7, k = t2 & 127;
        float v = (k < 64) ? h_re[n * 64 + k] : h_im[n * 64 + (k - 64)];
        Af16[t2] = (_Float16)v;
    } else if (tid < S3) {
        int e = tid - S2;
        atomicAdd(&counts[dst[e]], 1);
    }
}

// ---------------- K1_ws: weights-stationary f16 MFMA GEMM, XCD-colocated chunks --------
// grid = 1600; bijective decode: chunk = ((b>>6)<<3)|(b&7), cls = (b>>3)&7.
// The 8 cls-blocks of a chunk share b%8 => same XCD (round-robin) => Af16 chunk in one L2.
__global__ __launch_bounds__(256) void k1_ws(
    const _Float16* __restrict__ Af16,                // [NN][128]
    const _Float16* __restrict__ Btf,                 // [1024][128]
    unsigned* __restrict__ Whf, unsigned* __restrict__ Qhf) {
    int b = blockIdx.x;
    int chunk = ((b >> 6) << 3) | (b & 7);
    int cls = (b >> 3) & 7;
    if (chunk >= (NN + 255) / 256) return;
    int w = threadIdx.x >> 6, l = threadIdx.x & 63;
    int r = l & 15, g = l >> 4;
    int mh = cls >> 1, mat = cls & 1;
    int c0 = mh * 256 + mat * 128 + w * 16;
    int nbase = chunk * 256;
    unsigned* Out = mat ? Qhf : Whf;

    f16x8 Wf[2][4];
#pragma unroll
    for (int t = 0; t < 2; ++t)
#pragma unroll
        for (int ch = 0; ch < 4; ++ch)
            Wf[t][ch] = *(const f16x8*)(Btf + (c0 + t * 64 + r) * 128 + ch * 32 + g * 8);

    f16x8 N[3][4];
#pragma unroll
    for (int p = 0; p < 2; ++p) {
        int nc = min(nbase + p * 16 + r, NN - 1);
#pragma unroll
        for (int ch = 0; ch < 4; ++ch)
            N[p][ch] = *(const f16x8*)(Af16 + nc * 128 + ch * 32 + g * 8);
    }

#pragma unroll
    for (int nt = 0; nt < 16; ++nt) {
        const int cur = nt % 3;
        if (nt + 2 < 16) {
            const int nxt = (nt + 2) % 3;
            int nc = min(nbase + (nt + 2) * 16 + r, NN - 1);
#pragma unroll
            for (int ch = 0; ch < 4; ++ch)
                N[nxt][ch] = *(const f16x8*)(Af16 + nc * 128 + ch * 32 + g * 8);
        }
        f32x4 a0 = {0.f, 0.f, 0.f, 0.f}, a1 = {0.f, 0.f, 0.f, 0.f};
#pragma unroll
        for (int ch = 0; ch < 4; ++ch) {
            a0 = __builtin_amdgcn_mfma_f32_16x16x32_f16(Wf[0][ch], N[cur][ch], a0, 0, 0, 0);
            a1 = __builtin_amdgcn_mfma_f32_16x16x32_f16(Wf[1][ch], N[cur][ch], a1, 0, 0, 0);
        }
        int n = nbase + nt * 16 + r;
        if (n < NN) {
            uint4 u;
            u.x = pack_f16c(a0[0], a1[0]);
            u.y = pack_f16c(a0[1], a1[1]);
            u.z = pack_f16c(a0[2], a1[2]);
            u.w = pack_f16c(a0[3], a1[3]);
            *(uint4*)&Out[(n * HEADS + mh) * DIM + (c0 & 63) + g * 4] = u;
        }
    }
}

// ---------------- CSR build ----------------
__global__ __launch_bounds__(1024) void k2b_scan(const int* __restrict__ counts,
                                                 int* __restrict__ row_ptr, int* __restrict__ cursor) {
    __shared__ int buf[1024];
    int t = threadIdx.x;
    const int CH = (NN + 1023) / 1024;  // 49
    int i0 = t * CH;
    int i1 = min(i0 + CH, NN);
    int sum = 0;
    for (int i = i0; i < i1; ++i) sum += counts[i];
    buf[t] = sum;
    __syncthreads();
    for (int off = 1; off < 1024; off <<= 1) {
        int x = 0;
        if (t >= off) x = buf[t - off];
        __syncthreads();
        buf[t] += x;
        __syncthreads();
    }
    int run = buf[t] - sum;
    for (int i = i0; i < i1; ++i) { row_ptr[i] = run; cursor[i] = run; run += counts[i]; }
    if (t == 1023) row_ptr[NN] = buf[1023];
}

__global__ void k2c_fill(const int* __restrict__ src, const int* __restrict__ dst,
                         int* __restrict__ cursor, int* __restrict__ sorted_src) {
    int e = blockIdx.x * blockDim.x + threadIdx.x;
    if (e < NE) {
        int pos = atomicAdd(&cursor[dst[e]], 1);
        sorted_src[pos] = src[e];
    }
}

// ---------------- K_main: 2 nodes per 128-thr block (1/wave), 2 edges via 32-lane halves,
//                  fdot2 + DPP, no-max softmax, 2-phase unrolled pipeline ----------------
__global__ __launch_bounds__(128) void k_main(
    const float* __restrict__ h_re, const float* __restrict__ h_im,
    const _Float16* __restrict__ Af16,       // [NN][128] (imag at +64)
    const uint4* __restrict__ Whf, const uint4* __restrict__ Qhf,  // f16 pairs
    const int* __restrict__ row_ptr, const int* __restrict__ sorted_src,
    _Float16* __restrict__ Sb, float2* __restrict__ T_out) {
    int wave = threadIdx.x >> 6;
    int lane = threadIdx.x & 63;
    int n = blockIdx.x * 2 + wave;   // NN even, grid = NN/2 exact
    int e = lane >> 5;               // half (edge slot)
    int g = (lane >> 3) & 3;         // head
    int l = lane & 7;                // dim block of 8
    int d0 = l * 8;

    float hre[8];
    f16x2 hd2[8], hdn2[8], qh2[8], qhn2[8];
    float tr = 0.f, ti = 0.f, nr = 0.f;
    {
        float4 a0 = *(const float4*)(h_re + n * DIM + d0);
        float4 a1 = *(const float4*)(h_re + n * DIM + d0 + 4);
        float4 b0 = *(const float4*)(h_im + n * DIM + d0);
        float4 b1 = *(const float4*)(h_im + n * DIM + d0 + 4);
        float hrev[8] = {a0.x, a0.y, a0.z, a0.w, a1.x, a1.y, a1.z, a1.w};
        float himv[8] = {b0.x, b0.y, b0.z, b0.w, b1.x, b1.y, b1.z, b1.w};
        const unsigned* qp = (const unsigned*)Qhf + (n * HEADS + g) * DIM + d0;
        uint4 q0 = *(const uint4*)qp;
        uint4 q1 = *(const uint4*)(qp + 4);
        unsigned qw[8] = {q0.x, q0.y, q0.z, q0.w, q1.x, q1.y, q1.z, q1.w};
#pragma unroll
        for (int j = 0; j < 8; ++j) {
            hre[j] = hrev[j];
            hd2[j][0] = (_Float16)hrev[j]; hd2[j][1] = (_Float16)himv[j];
            hdn2[j] = swapneg(hd2[j]);
            f16x2 q2 = __builtin_bit_cast(f16x2, qw[j]);
            qh2[j] = q2;
            qhn2[j] = swapneg(q2);
            float qre = (float)q2[0], qim = (float)q2[1];
            tr += qre * hrev[j] + qim * himv[j];
            ti += qre * himv[j] - qim * hrev[j];
            nr += hrev[j] * hrev[j] + himv[j] * himv[j];
        }
    }
    tr = dpp_red8(tr); ti = dpp_red8(ti); nr = dpp_red8(nr);
    float2 tnm = make_float2(tr, ti);
    float inv_n2 = 1.0f / fmaxf(nr, 1e-6f);

    int beg = row_ptr[n], end = row_ptr[n + 1];
    float l_run = 0.f, Tr = 0.f, Ti = 0.f;
    float Sr[8] = {0, 0, 0, 0, 0, 0, 0, 0}, Si[8] = {0, 0, 0, 0, 0, 0, 0, 0};

    // two edge-buffer sets (A: pos..pos+1, B: pos+2..pos+3), zero-init (invalid => zeros)
    float4 aR0 = make_float4(0, 0, 0, 0), aR1 = aR0, bR0 = aR0, bR1 = aR0;
    uint4 aIm = make_uint4(0, 0, 0, 0), aW0 = aIm, aW1 = aIm;
    uint4 bIm = aIm, bW0 = aIm, bW1 = aIm;
    auto ldE = [&](int idx, float4& r0_, float4& r1_, uint4& im_, uint4& w0_, uint4& w1_) {
        int s = sorted_src[idx];
        r0_ = *(const float4*)(h_re + s * DIM + d0);
        r1_ = *(const float4*)(h_re + s * DIM + d0 + 4);
        im_ = *(const uint4*)(Af16 + s * 128 + 64 + d0);
        const unsigned* wp = (const unsigned*)Whf + (s * HEADS + g) * DIM + d0;
        w0_ = *(const uint4*)wp;
        w1_ = *(const uint4*)(wp + 4);
    };
    auto process = [&](const float4& R0, const float4& R1, const uint4& Im,
                       const uint4& W0, const uint4& W1, bool valid) {
        float csr[8] = {R0.x, R0.y, R0.z, R0.w, R1.x, R1.y, R1.z, R1.w};
        float csi[8];
        {
            unsigned iw[4] = {Im.x, Im.y, Im.z, Im.w};
#pragma unroll
            for (int k = 0; k < 4; ++k) {
                f16x2 p = __builtin_bit_cast(f16x2, iw[k]);
                csi[2 * k] = (float)p[0];
                csi[2 * k + 1] = (float)p[1];
            }
        }
        unsigned ww[8] = {W0.x, W0.y, W0.z, W0.w, W1.x, W1.y, W1.z, W1.w};
        float r0 = 0, r1 = 0, r2 = 0, r3 = 0, r4 = 0;
#pragma unroll
        for (int j = 0; j < 8; ++j) {
            f16x2 w2 = __builtin_bit_cast(f16x2, ww[j]);
            r0 = __builtin_amdgcn_fdot2(w2, hd2[j], r0, false);
            r1 = __builtin_amdgcn_fdot2(w2, hdn2[j], r1, false);
            r2 = __builtin_amdgcn_fdot2(w2, qh2[j], r2, false);
            r3 = __builtin_amdgcn_fdot2(w2, qhn2[j], r3, false);
            r4 = fmaf(hre[j], csr[j], r4);
        }
        r0 = dpp_red8(r0); r1 = dpp_red8(r1); r2 = dpp_red8(r2);
        r3 = dpp_red8(r3); r4 = dpp_red8(r4);

        float sg = (r4 > 0.f) ? 1.f : ((r4 < 0.f) ? 0.f : 0.5f);
        float cre = SIC * r0 * inv_n2;
        float cim = SIC * r1 * inv_n2;
        float sre = r2 - (cre * tnm.x - cim * tnm.y);
        float sim_ = r3 - (cre * tnm.y + cim * tnm.x);
        float logit = sqrtf(sre * sre + sim_ * sim_) * 0.125f;
        float ex = valid ? __expf(logit) : 0.f;
        float wgt = ex * sg;
        l_run += ex;
#pragma unroll
        for (int j = 0; j < 8; ++j) {
            Sr[j] = fmaf(wgt, csr[j], Sr[j]);
            Si[j] = fmaf(wgt, csi[j], Si[j]);
        }
        Tr = fmaf(wgt, cre, Tr);
        Ti = fmaf(wgt, cim, Ti);
    };

    if (beg + e < end) ldE(beg + e, aR0, aR1, aIm, aW0, aW1);
    if (beg + 2 + e < end) ldE(beg + 2 + e, bR0, bR1, bIm, bW0, bW1);

    for (int pos = beg; pos < end; pos += 4) {
        process(aR0, aR1, aIm, aW0, aW1, (pos + e) < end);
        if (pos + 4 + e < end) ldE(pos + 4 + e, aR0, aR1, aIm, aW0, aW1);
        else { aR0 = make_float4(0, 0, 0, 0); aR1 = aR0; aIm = make_uint4(0, 0, 0, 0); aW0 = aIm; aW1 = aIm; }
        if (pos + 2 >= end) break;
        process(bR0, bR1, bIm, bW0, bW1, (pos + 2 + e) < end);
        if (pos + 6 + e < end) ldE(pos + 6 + e, bR0, bR1, bIm, bW0, bW1);
        else { bR0 = make_float4(0, 0, 0, 0); bR1 = bR0; bIm = make_uint4(0, 0, 0, 0); bW0 = bIm; bW1 = bIm; }
    }

    // merge the two halves (lane l and l+32 hold same (head, dims); same exp scale)
#pragma unroll
    for (int j = 0; j < 8; ++j) {
        Sr[j] += __shfl_xor(Sr[j], 32, 64);
        Si[j] += __shfl_xor(Si[j], 32, 64);
    }
    l_run += __shfl_xor(l_run, 32, 64);
    Tr += __shfl_xor(Tr, 32, 64);
    Ti += __shfl_xor(Ti, 32, 64);

    float inv = 1.0f / (l_run + 1e-16f);
    if (e == 0) {
        f16x8 s0, s1;
#pragma unroll
        for (int j = 0; j < 4; ++j) {
            s0[2 * j] = (_Float16)(Sr[j] * inv);     s0[2 * j + 1] = (_Float16)(Si[j] * inv);
            s1[2 * j] = (_Float16)(Sr[j + 4] * inv); s1[2 * j + 1] = (_Float16)(Si[j + 4] * inv);
        }
        _Float16* sp = Sb + n * 512 + g * 128 + d0 * 2;
        *(f16x8*)sp = s0;
        *(f16x8*)(sp + 8) = s1;
        if (l == 0) T_out[n * HEADS + g] = make_float2(Tr * inv, Ti * inv);
    }
}

// ---------------- K5_ws: nodes-stationary f16 MFMA GEMM + fused NodeNorm/ModReLU ------
// ch-outer / nt-inner: consecutive MFMAs target DIFFERENT acc => no dependency chain.
__global__ __launch_bounds__(256) void k5_ws(
    const float* __restrict__ h_re, const float* __restrict__ h_im,
    const _Float16* __restrict__ Sb,   // [NN][512]
    const float2* __restrict__ T_in,
    const _Float16* __restrict__ B2f,  // [128][512]
    const float* __restrict__ gate_raw, const float* __restrict__ modrelu_b,
    float2* __restrict__ out) {
    int w = threadIdx.x >> 6, l = threadIdx.x & 63;
    int n0 = blockIdx.x * 64 + w * 16;
    if (n0 >= NN) return;
    int r = l & 15, g = l >> 4;
    int nodeA = min(n0 + r, NN - 1);

    f16x8 A_[16];
#pragma unroll
    for (int ch = 0; ch < 16; ++ch)
        A_[ch] = *(const f16x8*)(Sb + nodeA * 512 + ch * 32 + g * 8);

    // B fragment for (nt, ch): B2f[(nt*16 + r)*512 + ch*32 + g*8]; slot = nt
    f16x8 Bf[8];
#pragma unroll
    for (int nt = 0; nt < 8; ++nt)
        Bf[nt] = *(const f16x8*)(B2f + (nt * 16 + r) * 512 + g * 8);

    f32x4 acc[8];
#pragma unroll
    for (int t = 0; t < 8; ++t) acc[t] = {0.f, 0.f, 0.f, 0.f};

#pragma unroll
    for (int ch = 0; ch < 16; ++ch) {
#pragma unroll
        for (int nt = 0; nt < 8; ++nt) {
            f16x8 b = Bf[nt];
            if (ch + 1 < 16)
                Bf[nt] = *(const f16x8*)(B2f + (nt * 16 + r) * 512 + (ch + 1) * 32 + g * 8);
            acc[nt] = __builtin_amdgcn_mfma_f32_16x16x32_f16(A_[ch], b, acc[nt], 0, 0, 0);
        }
    }

    float gate = 1.0f / (1.0f + expf(-gate_raw[0]));
    float bo[4];
#pragma unroll
    for (int q = 0; q < 4; ++q) bo[q] = modrelu_b[q * 16 + r];

#pragma unroll
    for (int j = 0; j < 4; ++j) {
        int n = n0 + g * 4 + j;
        int nc = min(n, NN - 1);
        float2 Ts = make_float2(0.f, 0.f);
#pragma unroll
        for (int m = 0; m < HEADS; ++m) {
            float2 tv = T_in[nc * HEADS + m];
            Ts.x += tv.x; Ts.y += tv.y;
        }
        float xr_[4], xi_[4];
        float sr = 0.f, si = 0.f, qr = 0.f, qi = 0.f;
#pragma unroll
        for (int q = 0; q < 4; ++q) {
            int o = q * 16 + r;
            float hr = h_re[nc * DIM + o];
            float hi = h_im[nc * DIM + o];
            float nre = hr + acc[q][j]     - gate * (Ts.x * hr - Ts.y * hi);
            float nim = hi + acc[q + 4][j] - gate * (Ts.x * hi + Ts.y * hr);
            xr_[q] = nre; xi_[q] = nim;
            sr += nre; si += nim; qr += nre * nre; qi += nim * nim;
        }
#pragma unroll
        for (int off = 1; off < 16; off <<= 1) {
            sr += __shfl_xor(sr, off, 64);
            si += __shfl_xor(si, off, 64);
            qr += __shfl_xor(qr, off, 64);
            qi += __shfl_xor(qi, off, 64);
        }
        float mean_r = sr * (1.f / DIM), mean_i = si * (1.f / DIM);
        float var_r = (qr - DIM * mean_r * mean_r) * (1.f / (DIM - 1));
        float var_i = (qi - DIM * mean_i * mean_i) * (1.f / (DIM - 1));
        float std_r = fmaxf(sqrtf(fmaxf(var_r, 0.f)), 1e-5f);
        float std_i = fmaxf(sqrtf(fmaxf(var_i, 0.f)), 1e-5f);
        if (n < NN) {
#pragma unroll
            for (int q = 0; q < 4; ++q) {
                float xr = (xr_[q] - mean_r) / std_r;
                float xi = (xi_[q] - mean_i) / std_i;
                float mag = fmaxf(sqrtf(xr * xr + xi * xi), 1e-6f);
                float gg = fmaxf(mag + bo[q], 0.f);
                float sc = gg / mag;
                out[n * DIM + q * 16 + r] = make_float2(xr * sc, xi * sc);
            }
        }
    }
}

extern "C" void kernel_launch(void* const* d_in, const int* in_sizes, int n_in,
                              void* d_out, int out_size, void* d_ws, size_t ws_size,
                              hipStream_t stream) {
    const float* h_re = (const float*)d_in[0];
    const float* h_im = (const float*)d_in[1];
    const float* W_re = (const float*)d_in[2];
    const float* W_im = (const float*)d_in[3];
    const float* Q_re = (const float*)d_in[4];
    const float* Q_im = (const float*)d_in[5];
    const float* gate_raw = (const float*)d_in[6];
    const float* b = (const float*)d_in[7];
    const int* src = (const int*)d_in[8];
    const int* dst = (const int*)d_in[9];

    char* ws = (char*)d_ws;
    size_t off = 0;
    auto alloc = [&](size_t bytes) {
        void* p = ws + off;
        off = (off + bytes + 255) & ~(size_t)255;
        return p;
    };
    _Float16* Btf = (_Float16*)alloc((size_t)1024 * 128 * sizeof(_Float16));
    _Float16* B2f = (_Float16*)alloc((size_t)128 * 512 * sizeof(_Float16));
    _Float16* Af16 = (_Float16*)alloc((size_t)NN * 128 * sizeof(_Float16));
    unsigned* Whf = (unsigned*)alloc((size_t)NN * HEADS * DIM * sizeof(unsigned));
    unsigned* Qhf = (unsigned*)alloc((size_t)NN * HEADS * DIM * sizeof(unsigned));
    _Float16* Sb = (_Float16*)alloc((size_t)NN * 512 * sizeof(_Float16));
    float2* T_buf = (float2*)alloc((size_t)NN * HEADS * sizeof(float2));
    int* counts = (int*)alloc((size_t)NN * sizeof(int));
    int* row_ptr = (int*)alloc((size_t)(NN + 1) * sizeof(int));
    int* cursor = (int*)alloc((size_t)NN * sizeof(int));
    int* sorted_src = (int*)alloc((size_t)NE * sizeof(int));

    hipMemsetAsync(counts, 0, (size_t)NN * sizeof(int), stream);
    k_pre<<<(S3 + 255) / 256, 256, 0, stream>>>(h_re, h_im, W_re, W_im, Q_re, Q_im, dst,
                                                Btf, B2f, Af16, counts);
    k1_ws<<<1600, 256, 0, stream>>>(Af16, Btf, Whf, Qhf);
    k2b_scan<<<1, 1024, 0, stream>>>(counts, row_ptr, cursor);
    k2c_fill<<<(NE + 255) / 256, 256, 0, stream>>>(src, dst, cursor, sorted_src);
    k_main<<<NN / 2, 128, 0, stream>>>(h_re, h_im, Af16, (const uint4*)Whf, (const uint4*)Qhf,
                                       row_ptr, sorted_src, Sb, T_buf);
    k5_ws<<<(NN + 63) / 64, 256, 0, stream>>>(h_re, h_im, Sb, T_buf, B2f,
                                              gate_raw, b, (float2*)d_out);
}